// Round 12
// baseline (198.028 us; speedup 1.0000x reference)
//
#include <hip/hip_runtime.h>
#include <math.h>

static constexpr int Bn = 2048;   // batch
static constexpr int Nn = 256;    // memory locations
static constexpr int Mn = 128;    // memory width
static constexpr int Un = 512;    // units

// Workspace layout (f32 offsets)
static constexpr size_t OFF_MNORM = 4608;     // 256
static constexpr size_t OFF_APREV = 4864;     // 1024
static constexpr size_t OFF_BIASH = 5888;     // 1152
static constexpr size_t OFF_KMAT  = 16384;                           // f32 [8192][256]; doubles as ZX bf16 [2048][2048]
static constexpr size_t OFF_HEADS = OFF_KMAT + 2097152;              // f32 [2048][1048]
static constexpr size_t OFF_AT    = OFF_HEADS + 2146304;             // f32 [2][2048][256]
static constexpr size_t OFF_ERA   = OFF_AT + 1048576;                // f32 [2048][2][128]
static constexpr size_t OFF_ADD   = OFF_ERA + 524288;
static constexpr size_t OFF_XHB   = OFF_ADD + 524288;                // bf16 [2048][1024]
static constexpr size_t OFF_HCAT  = OFF_XHB + 1048576;               // bf16 [2048][1024]
static constexpr size_t OFF_W0T   = OFF_HCAT + 1048576;              // bf16 [2048][512]
static constexpr size_t OFF_W1T   = OFF_W0T + 524288;                // bf16 [2048][1024]
static constexpr size_t OFF_WRWT  = OFF_W1T + 1048576;               // bf16 [1152][512]
static constexpr size_t OFF_WCOMB = OFF_WRWT + 294912;               // bf16 [512][1024]
static constexpr size_t OFF_WR2T  = OFF_WCOMB + 262144;              // bf16 [512][256]
static constexpr size_t OFF_M0B   = OFF_WR2T + 65536;                // bf16 [256][128]
static constexpr size_t OFF_ZPART = OFF_M0B + 16384;                 // f32 [2][8][2048]
static constexpr size_t OFF_YH    = OFF_ZPART + 32768;               // f32 [2048][512]

// k_prep (dispatch 1) block table
static constexpr int P_X0  = 0;            // cvt8 X        (512)
static constexpr int P_M0  = 512;          // cvt8 m0       (16)
static constexpr int P_W0  = 528;          // cvtT W0 gate  (64x16)
static constexpr int P_W1  = 1552;         // cvtT W1 gate  (64x32)
static constexpr int P_WR2 = 3600;         // cvtT W_ou r   (16x8)
static constexpr int P_CA  = 3728;         // const-a       (1)
static constexpr int P_ZC  = 3729;         // zpart L0      (64)
static constexpr int P_END = 3793;

// k_mid (dispatch 2) block table — 128^2 tiles
static constexpr int M_L0  = 0;            // LSTM0 GEMM    (256 = 16x16)
static constexpr int M_ZX  = 256;          // ZX GEMM       (256 = 16x16)
static constexpr int M_PF  = 512;          // pfold         (16 = 4x2x2)
static constexpr int M_WRr = 528;          // cvtT W_r      (144)
static constexpr int M_WRw = 672;          // cvtT W_w      (400)
static constexpr int M_WOU = 1072;         // cvtT W_ou h   (256)
static constexpr int M_ZC1 = 1328;         // zpart L1      (64)
static constexpr int M_END = 1392;

// k_heads (dispatch 4) block table — 128^2 tiles
static constexpr int H_HD  = 0;            // heads GEMM    (144 = 16x9)
static constexpr int H_YH  = 144;          // yh GEMM       (64 = 16x4)
static constexpr int H_END = 208;

// k_tail (dispatch 7) block table — 128^2 tiles
static constexpr int T_OUT = 0;            // out GEMM      (64 = 16x4)
static constexpr int T_MEM = 64;           // memt          (256)
static constexpr int T_END = 320;

#define DEV __device__ __forceinline__

typedef __attribute__((ext_vector_type(8))) short bf16x8;
typedef __attribute__((ext_vector_type(4))) float f32x4;
typedef __attribute__((ext_vector_type(8))) unsigned short ushort8;
typedef unsigned int u32;

DEV float sigf(float x) { return 1.0f / (1.0f + expf(-x)); }
DEV float softplusf(float x) { return x > 20.0f ? x : log1pf(expf(x)); }
DEV unsigned short f2bf(float f) {   // RNE float->bf16
    unsigned u = __float_as_uint(f);
    u = (u + 0x7FFFu + ((u >> 16) & 1u)) >> 16;
    return (unsigned short)u;
}
DEV float b2f(unsigned short u) { return __uint_as_float((u32)u << 16); }
DEV void gload16(const unsigned short* g, unsigned short* l) {
    __builtin_amdgcn_global_load_lds(
        (const __attribute__((address_space(1))) u32*)g,
        (__attribute__((address_space(3))) u32*)l, 16, 0, 0);
}

// tree reductions (k_prep const block only)
DEV float blk_reduce_max(float v, float* red) {
    int tid = threadIdx.x;
    red[tid] = v; __syncthreads();
    for (int s = (int)blockDim.x >> 1; s > 0; s >>= 1) {
        if (tid < s) red[tid] = fmaxf(red[tid], red[tid + s]);
        __syncthreads();
    }
    float r = red[0]; __syncthreads();
    return r;
}
DEV float blk_reduce_sum(float v, float* red) {
    int tid = threadIdx.x;
    red[tid] = v; __syncthreads();
    for (int s = (int)blockDim.x >> 1; s > 0; s >>= 1) {
        if (tid < s) red[tid] += red[tid + s];
        __syncthreads();
    }
    float r = red[0]; __syncthreads();
    return r;
}

// wave-shuffle reductions for 256-thread blocks
DEV float wv_sum(float v) {
    #pragma unroll
    for (int off = 32; off; off >>= 1) v += __shfl_xor(v, off);
    return v;
}
DEV float wv_max(float v) {
    #pragma unroll
    for (int off = 32; off; off >>= 1) v = fmaxf(v, __shfl_xor(v, off));
    return v;
}
DEV float blk_sum4(float v, float* red4) {
    v = wv_sum(v);
    int w = threadIdx.x >> 6;
    if ((threadIdx.x & 63) == 0) red4[w] = v;
    __syncthreads();
    float r = red4[0] + red4[1] + red4[2] + red4[3];
    __syncthreads();
    return r;
}
DEV float blk_max4(float v, float* red4) {
    v = wv_max(v);
    int w = threadIdx.x >> 6;
    if ((threadIdx.x & 63) == 0) red4[w] = v;
    __syncthreads();
    float r = fmaxf(fmaxf(red4[0], red4[1]), fmaxf(red4[2], red4[3]));
    __syncthreads();
    return r;
}

// ===========================================================================
// GEMM machinery: 128x128 tile (m97 structure), 4 waves (2x2), per-wave
// 64x64 (acc[4][4]) — MFMA:ds_read = 2.0 per K-step. BK=64, dbuf LDS via
// global_load_lds (16B), XOR-swizzle via pre-swizzled source k-offset,
// T4 counted-vmcnt mainloop (8 loads/thread/stage).
// ===========================================================================
#define GEMM_SHARED                                                             \
    __shared__ __align__(16) unsigned short As[2][128 * 64];                    \
    __shared__ __align__(16) unsigned short Ws[2][128 * 64];

#define GEMM_REGS                                                               \
    const int tid  = threadIdx.x;                                               \
    const int lane = tid & 63;                                                  \
    const int wave = tid >> 6;                                                  \
    const int wr = wave >> 1, wc = wave & 1;                                    \
    const int ke = ((tid & 7) * 8) ^ (((tid >> 3) & 7) << 3);                   \
    const int frow = lane & 15;                                                 \
    const int fko  = (lane >> 4) * 8;                                           \
    const int fxm  = (frow & 7) << 3;                                           \
    f32x4 acc[4][4];                                                            \
    _Pragma("unroll")                                                           \
    for (int i = 0; i < 4; ++i)                                                 \
        _Pragma("unroll")                                                       \
        for (int j = 0; j < 4; ++j) acc[i][j] = (f32x4){0.f, 0.f, 0.f, 0.f};

#define GEMM_STAGE(buf, k0)                                                     \
    {                                                                           \
        _Pragma("unroll")                                                       \
        for (int q = 0; q < 4; ++q)                                             \
            gload16(A  + (size_t)(row0 + q * 32 + (tid >> 3)) * lda + (k0) + ke,\
                    &As[buf][q * 2048 + tid * 8]);                              \
        _Pragma("unroll")                                                       \
        for (int q = 0; q < 4; ++q)                                             \
            gload16(Wt + (size_t)(col0 + q * 32 + (tid >> 3)) * ldw + (k0) + ke,\
                    &Ws[buf][q * 2048 + tid * 8]);                              \
    }

#define GEMM_FRAGS_AND_MFMA(Ab, Wb)                                             \
    {                                                                           \
        bf16x8 af[2][4], wf[2][4];                                              \
        _Pragma("unroll")                                                       \
        for (int kk = 0; kk < 2; ++kk) {                                        \
            _Pragma("unroll")                                                   \
            for (int i = 0; i < 4; ++i) {                                       \
                int fr = wr * 64 + i * 16 + frow;                               \
                af[kk][i] = *(const bf16x8*)&(Ab)[fr * 64 + ((kk * 32 + fko) ^ fxm)]; \
            }                                                                   \
            _Pragma("unroll")                                                   \
            for (int j = 0; j < 4; ++j) {                                       \
                int fr = wc * 64 + j * 16 + frow;                               \
                wf[kk][j] = *(const bf16x8*)&(Wb)[fr * 64 + ((kk * 32 + fko) ^ fxm)]; \
            }                                                                   \
        }                                                                       \
        __builtin_amdgcn_s_setprio(1);                                          \
        _Pragma("unroll")                                                       \
        for (int kk = 0; kk < 2; ++kk)                                          \
            _Pragma("unroll")                                                   \
            for (int i = 0; i < 4; ++i)                                         \
                _Pragma("unroll")                                               \
                for (int j = 0; j < 4; ++j)                                     \
                    acc[i][j] = __builtin_amdgcn_mfma_f32_16x16x32_bf16(        \
                        af[kk][i], wf[kk][j], acc[i][j], 0, 0, 0);              \
        __builtin_amdgcn_s_setprio(0);                                          \
    }

#define GEMM_MAINLOOP(Kr)                                                       \
    {                                                                           \
        const int nt = (Kr) >> 6;                                               \
        int cur = 0;                                                            \
        GEMM_STAGE(0, 0);                                                       \
        for (int t = 0; t < nt; ++t) {                                          \
            if (t + 1 < nt) {                                                   \
                GEMM_STAGE(cur ^ 1, (t + 1) * 64);                              \
                asm volatile("s_waitcnt vmcnt(8)" ::: "memory");                \
            } else {                                                            \
                asm volatile("s_waitcnt vmcnt(0)" ::: "memory");                \
            }                                                                   \
            __builtin_amdgcn_sched_barrier(0);                                  \
            __builtin_amdgcn_s_barrier();                                       \
            __builtin_amdgcn_sched_barrier(0);                                  \
            GEMM_FRAGS_AND_MFMA(As[cur], Ws[cur]);                              \
            __builtin_amdgcn_sched_barrier(0);                                  \
            __builtin_amdgcn_s_barrier();                                       \
            cur ^= 1;                                                           \
        }                                                                       \
    }

// LSTM epilogue: gate-permuted cols, fused split-K zc reduce + optional ZX
// (bf16 [row][2048 permuted cols]) + cell nonlinearity.
#define LSTM_EPILOGUE(zc, doclip, houtp, ldhv, ZXP)                             \
    {                                                                           \
        const int uu = lane & 15;                                               \
        const int q  = (col0 >> 6) + wc;                                        \
        const int uq = q * 16 + uu;                                             \
        const float c0v = c0[(zc) * 512 + uq];                                  \
        float bg[4];                                                            \
        _Pragma("unroll")                                                       \
        for (int g = 0; g < 4; ++g) {                                           \
            int j = g * 512 + q * 16 + uu;                                      \
            float a = b_lstm[(zc) * 2048 + j];                                  \
            _Pragma("unroll")                                                   \
            for (int p = 0; p < 8; ++p)                                         \
                a += zpart[((size_t)(zc) * 8 + p) * 2048 + j];                  \
            bg[g] = a;                                                          \
        }                                                                       \
        _Pragma("unroll")                                                       \
        for (int i = 0; i < 4; ++i) {                                           \
            int rbase = row0 + wr * 64 + i * 16 + (lane >> 4) * 4;              \
            _Pragma("unroll")                                                   \
            for (int r = 0; r < 4; ++r) {                                       \
                float z0 = 0.f, z1 = 0.f, z2 = 0.f, z3 = 0.f;                   \
                if (ZXP) {                                                      \
                    const unsigned short* zr = (ZXP) +                          \
                        (size_t)(rbase + r) * 2048 + q * 64 + uu;               \
                    z0 = b2f(zr[0]);  z1 = b2f(zr[16]);                         \
                    z2 = b2f(zr[32]); z3 = b2f(zr[48]);                         \
                }                                                               \
                float ig = acc[i][0][r] + bg[0] + z0;                           \
                float fg = acc[i][1][r] + bg[1] + z1;                           \
                float gg = acc[i][2][r] + bg[2] + z2;                           \
                float og = acc[i][3][r] + bg[3] + z3;                           \
                float c = sigf(fg) * c0v + sigf(ig) * tanhf(gg);                \
                float h = sigf(og) * tanhf(c);                                  \
                if (doclip) h = fminf(fmaxf(h, -20.f), 20.f);                   \
                (houtp)[(size_t)(rbase + r) * (ldhv) + uq] = f2bf(h);           \
            }                                                                   \
        }                                                                       \
    }

// ---------------------------------------------------------------------------
// prep device helpers
DEV void dev_cvt8(const float* src, int lds, unsigned short* dst, int ldd,
                  int c8, int bloc, int tid)
{
    size_t idx = (size_t)bloc * 256 + tid;
    size_t r = idx / c8, c = (idx % c8) * 8;
    const float* s = src + r * lds + c;
    float4 v0 = *(const float4*)s;
    float4 v1 = *(const float4*)(s + 4);
    ushort8 o;
    o[0] = f2bf(v0.x); o[1] = f2bf(v0.y); o[2] = f2bf(v0.z); o[3] = f2bf(v0.w);
    o[4] = f2bf(v1.x); o[5] = f2bf(v1.y); o[6] = f2bf(v1.z); o[7] = f2bf(v1.w);
    *(ushort8*)(dst + r * ldd + c) = o;
}

DEV void dev_cvtT(const float* src, int R, int C, int lds,
                  unsigned short* dst, int ldd, int mode, int bx, int by,
                  int tid, float* t /*32x33*/)
{
    const int x = tid & 31;
    for (int y = tid >> 5; y < 32; y += 8) {
        int r = by * 32 + y, c = bx * 32 + x;
        int scol = c;
        if (mode) scol = ((c >> 4) & 3) * 512 + (c >> 6) * 16 + (c & 15);
        t[y * 33 + x] = (r < R && c < C) ? src[(size_t)r * lds + scol] : 0.f;
    }
    __syncthreads();
    for (int y = tid >> 5; y < 32; y += 8) {
        int c = bx * 32 + y, r = by * 32 + x;
        if (c < C && r < R) dst[(size_t)c * ldd + r] = f2bf(t[x * 33 + y]);
    }
}

// ===========================================================================
// Dispatch 1 — k_prep
// ===========================================================================
__global__ __launch_bounds__(256) void k_prep(
    const float* __restrict__ X, const float* __restrict__ m0,
    const float* __restrict__ H0, const float* __restrict__ R0,
    const float* __restrict__ A0, const float* __restrict__ W_prep,
    const float* __restrict__ b_prep, const float* __restrict__ W_lstm,
    const float* __restrict__ b_r, const float* __restrict__ b_w,
    const float* __restrict__ W_ou, float* __restrict__ ws)
{
    __shared__ float sh[32 * 33 + 64];
    const int bid = blockIdx.x, tid = threadIdx.x;
    unsigned short* XHB  = (unsigned short*)(ws + OFF_XHB);
    unsigned short* W0T  = (unsigned short*)(ws + OFF_W0T);
    unsigned short* W1T  = (unsigned short*)(ws + OFF_W1T);
    unsigned short* WR2T = (unsigned short*)(ws + OFF_WR2T);
    unsigned short* M0B  = (unsigned short*)(ws + OFF_M0B);

    if (bid < P_M0) {
        dev_cvt8(X, 512, XHB, 1024, 64, bid - P_X0, tid);
    } else if (bid < P_W0) {
        dev_cvt8(m0, 128, M0B, 128, 16, bid - P_M0, tid);
    } else if (bid < P_W1) {
        int s = bid - P_W0;
        dev_cvtT(W_lstm, 512, 2048, 2048, W0T, 512, 1, s & 63, s >> 6, tid, sh);
    } else if (bid < P_WR2) {
        int s = bid - P_W1;
        dev_cvtT(W_lstm + (size_t)1536 * 2048, 1024, 2048, 2048, W1T, 1024, 1,
                 s & 63, s >> 6, tid, sh);
    } else if (bid < P_CA) {
        int s = bid - P_WR2;
        dev_cvtT(W_ou + (size_t)512 * 512, 256, 512, 512, WR2T, 256, 0,
                 s & 15, s >> 4, tid, sh);
    } else if (bid < P_ZC) {
        float* red = sh;
        for (int i = 0; i < 4; ++i) {
            float v = A0[i * 256 + tid];
            float mx = blk_reduce_max(v, red);
            float e = expf(v - mx);
            float s = blk_reduce_sum(e, red);
            ws[OFF_APREV + i * 256 + tid] = e / s;
        }
        float acc = 0.f;
        for (int m = 0; m < 128; ++m) {
            float t = m0[(size_t)tid * 128 + m];
            acc = fmaf(t, t, acc);
        }
        ws[OFF_MNORM + tid] = sqrtf(acc);
        for (int j = tid; j < 1152; j += 256)
            ws[OFF_BIASH + j] = (j < 268) ? b_r[j] : (j < 1048 ? b_w[j - 268] : 0.f);
    } else {
        // zpart layer 0
        int sub = bid - P_ZC;
        int colb = sub & 7, up = sub >> 3;
        int j = colb * 256 + tid;
        float acc = 0.f;
        if (up < 4) {
            sh[256 + tid] = tanhf(R0[tid]);
            __syncthreads();
            if (tid < 128) {
                int u = up * 128 + tid;
                float a = b_prep[u];
                for (int k = 0; k < 256; ++k)
                    a = fmaf(sh[256 + k], W_prep[(size_t)k * 512 + u], a);
                sh[tid] = a;
            }
            __syncthreads();
            const int u0 = up * 128;
            #pragma unroll 4
            for (int t = 0; t < 128; ++t)
                acc = fmaf(sh[t], W_lstm[(size_t)(512 + u0 + t) * 2048 + j], acc);
        } else {
            const int u0 = up * 128;
            #pragma unroll 4
            for (int t = 0; t < 128; ++t)
                acc = fmaf(H0[u0 - 512 + t],
                           W_lstm[(size_t)(512 + u0 + t) * 2048 + j], acc);
        }
        (ws + OFF_ZPART)[(size_t)up * 2048 + j] = acc;
    }
}

// ===========================================================================
// Dispatch 2 — k_mid: LSTM0 + ZX + pfold GEMMs (128^2) + late prep
// ===========================================================================
__global__ __launch_bounds__(256) void k_mid(
    const float* __restrict__ W_lstm, const float* __restrict__ W_r,
    const float* __restrict__ W_w, const float* __restrict__ W_ou,
    const float* __restrict__ H0, const float* __restrict__ b_lstm,
    const float* __restrict__ c0, float* __restrict__ ws)
{
    GEMM_SHARED
    const int s = blockIdx.x;
    float* sh = (float*)&As[0][0];   // alias for cvtT scratch
    unsigned short* XHB   = (unsigned short*)(ws + OFF_XHB);
    unsigned short* W0T   = (unsigned short*)(ws + OFF_W0T);
    unsigned short* W1T   = (unsigned short*)(ws + OFF_W1T);
    unsigned short* WRWT  = (unsigned short*)(ws + OFF_WRWT);
    unsigned short* WCOMB = (unsigned short*)(ws + OFF_WCOMB);
    unsigned short* WR2T  = (unsigned short*)(ws + OFF_WR2T);
    unsigned short* M0B   = (unsigned short*)(ws + OFF_M0B);
    unsigned short* ZX    = (unsigned short*)(ws + OFF_KMAT);
    const float* zpart    = ws + OFF_ZPART;

    if (s < M_WRr) {
        const unsigned short *A, *Wt;
        int lda, ldw, row0, col0, Kr, mode;
        unsigned short* pCb = nullptr;
        if (s < M_ZX) {
            mode = 0;
            A = XHB;  lda = 1024; Wt = W0T; ldw = 512;
            row0 = (s & 15) * 128; col0 = (s >> 4) * 128; Kr = 512;
        } else if (s < M_PF) {
            int p = s - M_ZX;
            mode = 1;
            A = XHB;  lda = 1024; Wt = W1T; ldw = 1024;   // k 0..511 = X part
            row0 = (p & 15) * 128; col0 = (p >> 4) * 128; Kr = 512;
        } else {
            int p = s - M_PF;                 // 0..15
            mode = 2;
            int pz = p >> 3, py = (p >> 2) & 1, px = p & 3;
            A = WR2T + pz * 128; lda = 256; Wt = M0B; ldw = 128;
            row0 = px * 128; col0 = py * 128; Kr = 128;
            pCb = WCOMB + 512 + pz * 256;
        }
        GEMM_REGS
        GEMM_MAINLOOP(Kr)
        if (mode == 0) {
            unsigned short* hout = XHB + 512;
            const unsigned short* zxn = nullptr;
            LSTM_EPILOGUE(0, 0, hout, 1024, zxn)
        } else if (mode == 1) {
            #pragma unroll
            for (int i = 0; i < 4; ++i) {
                int m0r = row0 + wr * 64 + i * 16 + (lane >> 4) * 4;
                #pragma unroll
                for (int j = 0; j < 4; ++j) {
                    int n = col0 + wc * 64 + j * 16 + (lane & 15);
                    #pragma unroll
                    for (int r = 0; r < 4; ++r)
                        ZX[(size_t)(m0r + r) * 2048 + n] = f2bf(acc[i][j][r]);
                }
            }
        } else {
            #pragma unroll
            for (int i = 0; i < 4; ++i) {
                int m0r = row0 + wr * 64 + i * 16 + (lane >> 4) * 4;
                #pragma unroll
                for (int j = 0; j < 4; ++j) {
                    int n = col0 + wc * 64 + j * 16 + (lane & 15);
                    #pragma unroll
                    for (int r = 0; r < 4; ++r)
                        pCb[(size_t)(m0r + r) * 1024 + n] = f2bf(acc[i][j][r]);
                }
            }
        }
    } else if (s < M_WRw) {
        int s2 = s - M_WRr;
        dev_cvtT(W_r, 512, 268, 268, WRWT, 512, 0, s2 % 9, s2 / 9, threadIdx.x, sh);
    } else if (s < M_WOU) {
        int s3 = s - M_WRw;
        dev_cvtT(W_w, 512, 780, 780, WRWT + (size_t)268 * 512, 512, 0,
                 s3 % 25, s3 / 25, threadIdx.x, sh);
    } else if (s < M_ZC1) {
        int s4 = s - M_WOU;
        dev_cvtT(W_ou, 512, 512, 512, WCOMB, 1024, 0, s4 & 15, s4 >> 4,
                 threadIdx.x, sh);
    } else {
        int s5 = s - M_ZC1;
        int colb = s5 & 7, up = s5 >> 3;
        int j = colb * 256 + threadIdx.x;
        const int u0 = up * 64;
        const float* W1 = W_lstm + (size_t)1536 * 2048;
        float acc = 0.f;
        #pragma unroll 4
        for (int t = 0; t < 64; ++t)
            acc = fmaf(H0[512 + u0 + t], W1[(size_t)(1024 + u0 + t) * 2048 + j], acc);
        (ws + OFF_ZPART)[((size_t)8 + up) * 2048 + j] = acc;
    }
}

// ===========================================================================
// Dispatch 3 — LSTM layer 1 (K=512 h1-part; ZX added in epilogue), 128^2
// ===========================================================================
__global__ __launch_bounds__(256) void gemm_lstm(
    const unsigned short* __restrict__ A, int lda,
    const unsigned short* __restrict__ Wt, int ldw,
    const float* __restrict__ zpart, const float* __restrict__ b_lstm,
    const float* __restrict__ c0, const unsigned short* __restrict__ ZXP,
    unsigned short* __restrict__ hout)
{
    GEMM_SHARED
    const int row0 = blockIdx.x * 128;
    const int col0 = blockIdx.y * 128;
    GEMM_REGS
    GEMM_MAINLOOP(512)
    LSTM_EPILOGUE(1, 1, hout, 1024, ZXP)
}

// ===========================================================================
// Dispatch 4 — k_heads: heads GEMM + yh GEMM, 128^2 tiles
// ===========================================================================
__global__ __launch_bounds__(256) void k_heads(
    const unsigned short* __restrict__ HCAT,
    const unsigned short* __restrict__ WRWT,
    const unsigned short* __restrict__ WCOMB,
    const float* __restrict__ biash,
    float* __restrict__ heads, float* __restrict__ yh)
{
    GEMM_SHARED
    const int s = blockIdx.x;
    const unsigned short* A = HCAT;  const int lda = 1024;
    const unsigned short* Wt;
    int ldw, row0, col0;
    if (s < H_YH) {
        Wt = WRWT; ldw = 512;
        row0 = (s & 15) * 128; col0 = (s >> 4) * 128;   // 16 x 9
    } else {
        int p = s - H_YH;
        Wt = WCOMB; ldw = 1024;
        row0 = (p & 15) * 128; col0 = (p >> 4) * 128;   // 16 x 4
    }
    GEMM_REGS
    GEMM_MAINLOOP(512)
    if (s < H_YH) {
        #pragma unroll
        for (int i = 0; i < 4; ++i) {
            int m0r = row0 + wr * 64 + i * 16 + (lane >> 4) * 4;
            #pragma unroll
            for (int j = 0; j < 4; ++j) {
                int n = col0 + wc * 64 + j * 16 + (lane & 15);
                if (n >= 1048) continue;
                float bv = biash[n];
                #pragma unroll
                for (int r = 0; r < 4; ++r)
                    heads[(size_t)(m0r + r) * 1048 + n] = acc[i][j][r] + bv;
            }
        }
    } else {
        #pragma unroll
        for (int i = 0; i < 4; ++i) {
            int m0r = row0 + wr * 64 + i * 16 + (lane >> 4) * 4;
            #pragma unroll
            for (int j = 0; j < 4; ++j) {
                int n = col0 + wc * 64 + j * 16 + (lane & 15);
                #pragma unroll
                for (int r = 0; r < 4; ++r)
                    yh[(size_t)(m0r + r) * 512 + n] = acc[i][j][r];
            }
        }
    }
}

// ===========================================================================
// Dispatch 5 — kmat GEMM with fused tanh k-prep, 128^2 (grid 64x2)
// ===========================================================================
__global__ __launch_bounds__(256) void gemm_kmat(
    const float* __restrict__ heads,
    const unsigned short* __restrict__ M0B,
    float* __restrict__ C)
{
    GEMM_SHARED
    const int row0 = blockIdx.x * 128;
    const int col0 = blockIdx.y * 128;
    GEMM_REGS

#define KMAT_STAGE(buf, k0)                                                     \
    {                                                                           \
        _Pragma("unroll")                                                       \
        for (int q = 0; q < 4; ++q) {                                           \
            int R = row0 + q * 32 + (tid >> 3);                                 \
            int b = R >> 2, ih = R & 3;                                         \
            int cb = (ih < 2) ? ih * 134 : 268 + (ih - 2) * 390;                \
            const float* hp = heads + (size_t)b * 1048 + cb + (k0) + ke;        \
            ushort8 o;                                                          \
            _Pragma("unroll")                                                   \
            for (int j = 0; j < 8; ++j) o[j] = f2bf(tanhf(hp[j]));              \
            *(ushort8*)&As[buf][q * 2048 + tid * 8] = o;                        \
        }                                                                       \
        _Pragma("unroll")                                                       \
        for (int q = 0; q < 4; ++q)                                             \
            gload16(M0B + (size_t)(col0 + q * 32 + (tid >> 3)) * 128 + (k0) + ke,\
                    &Ws[buf][q * 2048 + tid * 8]);                              \
    }

    int cur = 0;
    KMAT_STAGE(0, 0);
    for (int t = 0; t < 2; ++t) {
        __syncthreads();
        if (t == 0) KMAT_STAGE(1, 64);
        GEMM_FRAGS_AND_MFMA(As[cur], Ws[cur]);
        cur ^= 1;
    }
#undef KMAT_STAGE
    #pragma unroll
    for (int i = 0; i < 4; ++i) {
        int m0r = row0 + wr * 64 + i * 16 + (lane >> 4) * 4;
        #pragma unroll
        for (int j = 0; j < 4; ++j) {
            int n = col0 + wc * 64 + j * 16 + (lane & 15);
            #pragma unroll
            for (int r = 0; r < 4; ++r)
                C[(size_t)(m0r + r) * 256 + n] = acc[i][j][r];
        }
    }
}

// ===========================================================================
// Dispatch 6 — addressing (4 heads, shuffle reductions)
// ===========================================================================
__global__ __launch_bounds__(256) void k_addr(
    const float* __restrict__ heads, const float* __restrict__ kmat,
    const float* __restrict__ mnorm, const float* __restrict__ aprev,
    float* __restrict__ at, unsigned short* __restrict__ hcat,
    float* __restrict__ era, float* __restrict__ addv)
{
    __shared__ float red4[4];
    __shared__ float wgs[256];
    __shared__ float sc[6];
    const int b = blockIdx.x, i = blockIdx.y, tid = threadIdx.x;
    const int cb = (i < 2) ? i * 134 : 268 + (i - 2) * 390;
    const float* hd = heads + (size_t)b * 1048 + cb;
    float kv = (tid < 128) ? tanhf(hd[tid]) : 0.f;
    float kn = sqrtf(blk_sum4(kv * kv, red4));
    if (i >= 2 && tid < 128) {
        era [((size_t)b * 2 + (i - 2)) * 128 + tid] = sigf(hd[134 + tid]);
        addv[((size_t)b * 2 + (i - 2)) * 128 + tid] = tanhf(hd[262 + tid]);
    }
    if (tid == 0) {
        sc[0] = softplusf(hd[128]);
        sc[1] = sigf(hd[129]);
        float v0 = hd[130], v1 = hd[131], v2 = hd[132];
        float mx = fmaxf(v0, fmaxf(v1, v2));
        float e0 = expf(v0 - mx), e1 = expf(v1 - mx), e2 = expf(v2 - mx);
        float ssum = e0 + e1 + e2;
        sc[2] = e0 / ssum; sc[3] = e1 / ssum; sc[4] = e2 / ssum;
        sc[5] = softplusf(hd[133]);
    }
    __syncthreads();
    const float beta = sc[0], g = sc[1], s0 = sc[2], s1 = sc[3], s2 = sc[4],
                gamma = sc[5];
    float inner = kmat[((size_t)b * 4 + i) * 256 + tid];
    float K = inner / (kn * mnorm[tid] + 1e-8f);
    float x = beta * K;
    float mx = blk_max4(x, red4);
    float e = expf(x - mx);
    float se = blk_sum4(e, red4);
    float wc = e / se;
    float wg = g * wc + (1.f - g) * aprev[i * 256 + tid];
    wgs[tid] = wg;
    __syncthreads();
    float wconv = s0 * wg + s1 * wgs[(tid + 255) & 255] + s2 * wgs[(tid + 1) & 255];
    float wsh = powf(wconv, gamma);
    float ssum = blk_sum4(wsh, red4);
    float w = wsh / ssum;
    if (i < 2) hcat[(size_t)b * 1024 + 512 + i * 256 + tid] = f2bf(w);
    else       at[((size_t)(i - 2) * Bn + b) * 256 + tid] = w;
}

// ===========================================================================
// Dispatch 7 — k_tail: out GEMM (128^2, K=512, + yh + clip) + memt
// ===========================================================================
__global__ __launch_bounds__(256) void k_tail(
    const unsigned short* __restrict__ HCAT,
    const unsigned short* __restrict__ WCOMB,
    const float* __restrict__ yh, const float* __restrict__ b_ou,
    const float* __restrict__ m0, const float* __restrict__ at,
    const float* __restrict__ era, const float* __restrict__ addv,
    float* __restrict__ out)
{
    GEMM_SHARED
    const int s = blockIdx.x;
    if (s < T_MEM) {
        const unsigned short* A  = HCAT + 512;        const int lda = 1024;
        const unsigned short* Wt = WCOMB + 512;       const int ldw = 1024;
        const int row0 = (s & 15) * 128;
        const int col0 = (s >> 4) * 128;
        GEMM_REGS
        GEMM_MAINLOOP(512)
        #pragma unroll
        for (int i = 0; i < 4; ++i) {
            int m0r = row0 + wr * 64 + i * 16 + (lane >> 4) * 4;
            #pragma unroll
            for (int j = 0; j < 4; ++j) {
                int n = col0 + wc * 64 + j * 16 + (lane & 15);
                if (n >= 512) continue;
                float bv = b_ou[n];
                #pragma unroll
                for (int r = 0; r < 4; ++r) {
                    float v = acc[i][j][r] + bv + yh[(size_t)(m0r + r) * 512 + n];
                    out[(size_t)(m0r + r) * 512 + n] = fminf(fmaxf(v, -20.f), 20.f);
                }
            }
        }
    } else {
        // memt: 8 batch rows per block, m0 reused 8x, NT stores
        const int tid = threadIdx.x;
        const int b0 = (s - T_MEM) * 8;
        float (*at_s)[8][256] = (float(*)[8][256])(&As[0][0]);     // 16 KB
        float (*er_s)[8][128] = (float(*)[8][128])(&Ws[0][0]);     // 8 KB
        float (*ad_s)[8][128] = (float(*)[8][128])(&Ws[0][4096]);  // 8 KB
        for (int t = tid; t < 1024; t += 256) {
            int i = t >> 9, rem = t & 511;
            int bb = rem >> 6, n4 = rem & 63;
            ((float4*)&at_s[i][bb][0])[n4] =
                ((const float4*)(at + ((size_t)i * Bn + b0 + bb) * 256))[n4];
        }
        for (int t = tid; t < 512; t += 256) {
            int i = t >> 8, rem = t & 255;
            int bb = rem >> 5, m4 = rem & 31;
            ((float4*)&er_s[i][bb][0])[m4] =
                ((const float4*)(era + ((size_t)(b0 + bb) * 2 + i) * 128))[m4];
            ((float4*)&ad_s[i][bb][0])[m4] =
                ((const float4*)(addv + ((size_t)(b0 + bb) * 2 + i) * 128))[m4];
        }
        __syncthreads();
        const float4* m0v = (const float4*)m0;
        float4* outv = (float4*)(out + (size_t)Bn * Un);
        for (int pos = tid; pos < 8192; pos += 256) {
            int mq = pos & 31, n = pos >> 5;
            float4 t0 = m0v[pos];
            #pragma unroll
            for (int bb = 0; bb < 8; ++bb) {
                float w0 = at_s[0][bb][n], w1 = at_s[1][bb][n];
                float4 e0 = *(const float4*)&er_s[0][bb][mq * 4];
                float4 a0 = *(const float4*)&ad_s[0][bb][mq * 4];
                float4 e1 = *(const float4*)&er_s[1][bb][mq * 4];
                float4 a1 = *(const float4*)&ad_s[1][bb][mq * 4];
                float4 t = t0;
#define UPD(c) { t.c = t.c * (1.f - w0 * e0.c) + w0 * a0.c; \
                 t.c = t.c * (1.f - w1 * e1.c) + w1 * a1.c; }
                UPD(x) UPD(y) UPD(z) UPD(w)
#undef UPD
                __builtin_nontemporal_store(*(f32x4*)&t,
                    (f32x4*)&outv[(size_t)(b0 + bb) * 8192 + pos]);
            }
        }
    }
}

extern "C" void kernel_launch(void* const* d_in, const int* in_sizes, int n_in,
                              void* d_out, int out_size, void* d_ws, size_t ws_size,
                              hipStream_t stream)
{
    const float* X      = (const float*)d_in[0];
    const float* m0     = (const float*)d_in[1];
    const float* H0     = (const float*)d_in[2];
    const float* C0     = (const float*)d_in[3];
    const float* R0     = (const float*)d_in[4];
    const float* A0     = (const float*)d_in[5];
    const float* W_prep = (const float*)d_in[6];
    const float* b_prep = (const float*)d_in[7];
    const float* W_lstm = (const float*)d_in[8];
    const float* b_lstm = (const float*)d_in[9];
    const float* W_r    = (const float*)d_in[10];
    const float* b_r    = (const float*)d_in[11];
    const float* W_w    = (const float*)d_in[12];
    const float* b_w    = (const float*)d_in[13];
    const float* W_ou   = (const float*)d_in[14];
    const float* b_ou   = (const float*)d_in[15];
    float* ws  = (float*)d_ws;
    float* out = (float*)d_out;

    unsigned short* XHB   = (unsigned short*)(ws + OFF_XHB);
    unsigned short* HCAT  = (unsigned short*)(ws + OFF_HCAT);
    unsigned short* W1T   = (unsigned short*)(ws + OFF_W1T);
    unsigned short* WRWT  = (unsigned short*)(ws + OFF_WRWT);
    unsigned short* WCOMB = (unsigned short*)(ws + OFF_WCOMB);
    unsigned short* M0B   = (unsigned short*)(ws + OFF_M0B);
    unsigned short* ZX    = (unsigned short*)(ws + OFF_KMAT);

    // 1. critical prep
    k_prep<<<P_END, 256, 0, stream>>>(
        X, m0, H0, R0, A0, W_prep, b_prep, W_lstm, b_r, b_w, W_ou, ws);

    // 2. LSTM0 + ZX + pfold + late prep (concurrent)
    k_mid<<<M_END, 256, 0, stream>>>(
        W_lstm, W_r, W_w, W_ou, H0, b_lstm, C0, ws);

    // 3. LSTM layer 1
    gemm_lstm<<<dim3(16, 16), 256, 0, stream>>>(
        XHB + 512, 1024, W1T + 512, 1024, ws + OFF_ZPART, b_lstm, C0, ZX, HCAT);

    // 4. heads + yh
    k_heads<<<H_END, 256, 0, stream>>>(
        HCAT, WRWT, WCOMB, ws + OFF_BIASH, ws + OFF_HEADS, ws + OFF_YH);

    // 5. kmat (fused tanh)
    gemm_kmat<<<dim3(64, 2), 256, 0, stream>>>(
        ws + OFF_HEADS, M0B, ws + OFF_KMAT);

    // 6. addressing
    k_addr<<<dim3(Bn, 4), 256, 0, stream>>>(
        ws + OFF_HEADS, ws + OFF_KMAT, ws + OFF_MNORM, ws + OFF_APREV,
        ws + OFF_AT, HCAT, ws + OFF_ERA, ws + OFF_ADD);

    // 7. out GEMM + memt (overlapped)
    k_tail<<<T_END, 256, 0, stream>>>(
        HCAT, WCOMB, ws + OFF_YH, b_ou, m0, ws + OFF_AT, ws + OFF_ERA,
        ws + OFF_ADD, out);
}

// Round 13
// 173.451 us; speedup vs baseline: 1.1417x; 1.1417x over previous
//
#include <hip/hip_runtime.h>
#include <math.h>

static constexpr int Bn = 2048;   // batch
static constexpr int Nn = 256;    // memory locations
static constexpr int Mn = 128;    // memory width
static constexpr int Un = 512;    // units

// Workspace layout (f32 offsets)
static constexpr size_t OFF_MNORM = 4608;     // 256
static constexpr size_t OFF_APREV = 4864;     // 1024
static constexpr size_t OFF_BIASH = 5888;     // 1152
static constexpr size_t OFF_KMAT  = 16384;                           // f32 [8192][256]; doubles as ZX bf16 [2048][2048]
static constexpr size_t OFF_HEADS = OFF_KMAT + 2097152;              // f32 [2048][1048]
static constexpr size_t OFF_AT    = OFF_HEADS + 2146304;             // f32 [2][2048][256]
static constexpr size_t OFF_ERA   = OFF_AT + 1048576;                // f32 [2048][2][128]
static constexpr size_t OFF_ADD   = OFF_ERA + 524288;
static constexpr size_t OFF_XHB   = OFF_ADD + 524288;                // bf16 [2048][1024]
static constexpr size_t OFF_HCAT  = OFF_XHB + 1048576;               // bf16 [2048][1024]
static constexpr size_t OFF_W0T   = OFF_HCAT + 1048576;              // bf16 [2048][512]
static constexpr size_t OFF_W1T   = OFF_W0T + 524288;                // bf16 [2048][1024]
static constexpr size_t OFF_WRWT  = OFF_W1T + 1048576;               // bf16 [1152][512]
static constexpr size_t OFF_WCOMB = OFF_WRWT + 294912;               // bf16 [512][1024]
static constexpr size_t OFF_WR2T  = OFF_WCOMB + 262144;              // bf16 [512][256]
static constexpr size_t OFF_M0B   = OFF_WR2T + 65536;                // bf16 [256][128]
static constexpr size_t OFF_ZPART = OFF_M0B + 16384;                 // f32 [2][8][2048]
static constexpr size_t OFF_YH    = OFF_ZPART + 32768;               // f32 [2048][512]

// k_prep (dispatch 1) block table
static constexpr int P_X0  = 0;            // cvt8 X        (512)
static constexpr int P_M0  = 512;          // cvt8 m0       (16)
static constexpr int P_W0  = 528;          // cvtT W0 gate  (64x16)
static constexpr int P_W1  = 1552;         // cvtT W1 gate  (64x32)
static constexpr int P_WR2 = 3600;         // cvtT W_ou r   (16x8)
static constexpr int P_CA  = 3728;         // const-a       (1)
static constexpr int P_ZC  = 3729;         // zpart L0      (64)
static constexpr int P_END = 3793;

// k_mid (dispatch 2) block table
static constexpr int M_L0  = 0;            // LSTM0 GEMM    (512)
static constexpr int M_ZX  = 512;          // ZX GEMM       (512)
static constexpr int M_PF  = 1024;         // pfold         (32)
static constexpr int M_WRr = 1056;         // cvtT W_r      (144)
static constexpr int M_WRw = 1200;         // cvtT W_w      (400)
static constexpr int M_WOU = 1600;         // cvtT W_ou h   (256)
static constexpr int M_ZC1 = 1856;         // zpart L1      (64)
static constexpr int M_END = 1920;

// k_heads (dispatch 4) block table
static constexpr int H_HD  = 0;            // heads GEMM    (288)
static constexpr int H_YH  = 288;          // yh GEMM       (128)
static constexpr int H_END = 416;

// k_tail (dispatch 7) block table
static constexpr int T_OUT = 0;            // out GEMM K=512 (128)
static constexpr int T_MEM = 128;          // memt          (256)
static constexpr int T_END = 384;

#define DEV __device__ __forceinline__

typedef __attribute__((ext_vector_type(8))) short bf16x8;
typedef __attribute__((ext_vector_type(4))) float f32x4;
typedef __attribute__((ext_vector_type(8))) unsigned short ushort8;
typedef unsigned int u32;

DEV float sigf(float x) { return 1.0f / (1.0f + expf(-x)); }
DEV float softplusf(float x) { return x > 20.0f ? x : log1pf(expf(x)); }
DEV unsigned short f2bf(float f) {   // RNE float->bf16
    unsigned u = __float_as_uint(f);
    u = (u + 0x7FFFu + ((u >> 16) & 1u)) >> 16;
    return (unsigned short)u;
}
DEV float b2f(unsigned short u) { return __uint_as_float((u32)u << 16); }
DEV void gload16(const unsigned short* g, unsigned short* l) {
    __builtin_amdgcn_global_load_lds(
        (const __attribute__((address_space(1))) u32*)g,
        (__attribute__((address_space(3))) u32*)l, 16, 0, 0);
}

// tree reductions (k_prep const block only)
DEV float blk_reduce_max(float v, float* red) {
    int tid = threadIdx.x;
    red[tid] = v; __syncthreads();
    for (int s = (int)blockDim.x >> 1; s > 0; s >>= 1) {
        if (tid < s) red[tid] = fmaxf(red[tid], red[tid + s]);
        __syncthreads();
    }
    float r = red[0]; __syncthreads();
    return r;
}
DEV float blk_reduce_sum(float v, float* red) {
    int tid = threadIdx.x;
    red[tid] = v; __syncthreads();
    for (int s = (int)blockDim.x >> 1; s > 0; s >>= 1) {
        if (tid < s) red[tid] += red[tid + s];
        __syncthreads();
    }
    float r = red[0]; __syncthreads();
    return r;
}

// wave-shuffle reductions for 256-thread blocks
DEV float wv_sum(float v) {
    #pragma unroll
    for (int off = 32; off; off >>= 1) v += __shfl_xor(v, off);
    return v;
}
DEV float wv_max(float v) {
    #pragma unroll
    for (int off = 32; off; off >>= 1) v = fmaxf(v, __shfl_xor(v, off));
    return v;
}
DEV float blk_sum4(float v, float* red4) {
    v = wv_sum(v);
    int w = threadIdx.x >> 6;
    if ((threadIdx.x & 63) == 0) red4[w] = v;
    __syncthreads();
    float r = red4[0] + red4[1] + red4[2] + red4[3];
    __syncthreads();
    return r;
}
DEV float blk_max4(float v, float* red4) {
    v = wv_max(v);
    int w = threadIdx.x >> 6;
    if ((threadIdx.x & 63) == 0) red4[w] = v;
    __syncthreads();
    float r = fmaxf(fmaxf(red4[0], red4[1]), fmaxf(red4[2], red4[3]));
    __syncthreads();
    return r;
}

// ===========================================================================
// GEMM machinery: 64x128 tile, 4 waves (2x2), BK=64, dbuf LDS via
// global_load_lds (16B), XOR-swizzle via pre-swizzled source k-offset,
// T4 counted-vmcnt mainloop. (R11 configuration — empirically best.)
// ===========================================================================
#define GEMM_SHARED                                                             \
    __shared__ __align__(16) unsigned short As[2][64 * 64];                     \
    __shared__ __align__(16) unsigned short Ws[2][128 * 64];

#define GEMM_REGS                                                               \
    const int tid  = threadIdx.x;                                               \
    const int lane = tid & 63;                                                  \
    const int wave = tid >> 6;                                                  \
    const int wr = wave >> 1, wc = wave & 1;                                    \
    const int ke = ((tid & 7) * 8) ^ (((tid >> 3) & 7) << 3);                   \
    const int frow = lane & 15;                                                 \
    const int fko  = (lane >> 4) * 8;                                           \
    const int fxm  = (frow & 7) << 3;                                           \
    f32x4 acc[2][4];                                                            \
    _Pragma("unroll")                                                           \
    for (int i = 0; i < 2; ++i)                                                 \
        _Pragma("unroll")                                                       \
        for (int j = 0; j < 4; ++j) acc[i][j] = (f32x4){0.f, 0.f, 0.f, 0.f};

#define GEMM_STAGE(buf, k0)                                                     \
    {                                                                           \
        _Pragma("unroll")                                                       \
        for (int q = 0; q < 2; ++q)                                             \
            gload16(A  + (size_t)(row0 + q * 32 + (tid >> 3)) * lda + (k0) + ke,\
                    &As[buf][q * 2048 + tid * 8]);                              \
        _Pragma("unroll")                                                       \
        for (int q = 0; q < 4; ++q)                                             \
            gload16(Wt + (size_t)(col0 + q * 32 + (tid >> 3)) * ldw + (k0) + ke,\
                    &Ws[buf][q * 2048 + tid * 8]);                              \
    }

#define GEMM_FRAGS_AND_MFMA(Ab, Wb)                                             \
    {                                                                           \
        bf16x8 af[2][2], wf[2][4];                                              \
        _Pragma("unroll")                                                       \
        for (int kk = 0; kk < 2; ++kk) {                                        \
            _Pragma("unroll")                                                   \
            for (int i = 0; i < 2; ++i) {                                       \
                int fr = wr * 32 + i * 16 + frow;                               \
                af[kk][i] = *(const bf16x8*)&(Ab)[fr * 64 + ((kk * 32 + fko) ^ fxm)]; \
            }                                                                   \
            _Pragma("unroll")                                                   \
            for (int j = 0; j < 4; ++j) {                                       \
                int fr = wc * 64 + j * 16 + frow;                               \
                wf[kk][j] = *(const bf16x8*)&(Wb)[fr * 64 + ((kk * 32 + fko) ^ fxm)]; \
            }                                                                   \
        }                                                                       \
        __builtin_amdgcn_s_setprio(1);                                          \
        _Pragma("unroll")                                                       \
        for (int kk = 0; kk < 2; ++kk)                                          \
            _Pragma("unroll")                                                   \
            for (int i = 0; i < 2; ++i)                                         \
                _Pragma("unroll")                                               \
                for (int j = 0; j < 4; ++j)                                     \
                    acc[i][j] = __builtin_amdgcn_mfma_f32_16x16x32_bf16(        \
                        af[kk][i], wf[kk][j], acc[i][j], 0, 0, 0);              \
        __builtin_amdgcn_s_setprio(0);                                          \
    }

#define GEMM_MAINLOOP(Kr)                                                       \
    {                                                                           \
        const int nt = (Kr) >> 6;                                               \
        int cur = 0;                                                            \
        GEMM_STAGE(0, 0);                                                       \
        for (int t = 0; t < nt; ++t) {                                          \
            if (t + 1 < nt) {                                                   \
                GEMM_STAGE(cur ^ 1, (t + 1) * 64);                              \
                asm volatile("s_waitcnt vmcnt(6)" ::: "memory");                \
            } else {                                                            \
                asm volatile("s_waitcnt vmcnt(0)" ::: "memory");                \
            }                                                                   \
            __builtin_amdgcn_sched_barrier(0);                                  \
            __builtin_amdgcn_s_barrier();                                       \
            __builtin_amdgcn_sched_barrier(0);                                  \
            GEMM_FRAGS_AND_MFMA(As[cur], Ws[cur]);                              \
            __builtin_amdgcn_sched_barrier(0);                                  \
            __builtin_amdgcn_s_barrier();                                       \
            cur ^= 1;                                                           \
        }                                                                       \
    }

// LSTM epilogue: gate-permuted cols, fused split-K zc reduce + optional ZX
// (bf16 [row][2048 permuted cols]) + cell nonlinearity.
#define LSTM_EPILOGUE(zc, doclip, houtp, ldhv, ZXP)                             \
    {                                                                           \
        const int uu = lane & 15;                                               \
        const int q  = (col0 >> 6) + wc;                                        \
        const int uq = q * 16 + uu;                                             \
        const float c0v = c0[(zc) * 512 + uq];                                  \
        float bg[4];                                                            \
        _Pragma("unroll")                                                       \
        for (int g = 0; g < 4; ++g) {                                           \
            int j = g * 512 + q * 16 + uu;                                      \
            float a = b_lstm[(zc) * 2048 + j];                                  \
            _Pragma("unroll")                                                   \
            for (int p = 0; p < 8; ++p)                                         \
                a += zpart[((size_t)(zc) * 8 + p) * 2048 + j];                  \
            bg[g] = a;                                                          \
        }                                                                       \
        _Pragma("unroll")                                                       \
        for (int i = 0; i < 2; ++i) {                                           \
            int rbase = row0 + wr * 32 + i * 16 + (lane >> 4) * 4;              \
            _Pragma("unroll")                                                   \
            for (int r = 0; r < 4; ++r) {                                       \
                float z0 = 0.f, z1 = 0.f, z2 = 0.f, z3 = 0.f;                   \
                if (ZXP) {                                                      \
                    const unsigned short* zr = (ZXP) +                          \
                        (size_t)(rbase + r) * 2048 + q * 64 + uu;               \
                    z0 = b2f(zr[0]);  z1 = b2f(zr[16]);                         \
                    z2 = b2f(zr[32]); z3 = b2f(zr[48]);                         \
                }                                                               \
                float ig = acc[i][0][r] + bg[0] + z0;                           \
                float fg = acc[i][1][r] + bg[1] + z1;                           \
                float gg = acc[i][2][r] + bg[2] + z2;                           \
                float og = acc[i][3][r] + bg[3] + z3;                           \
                float c = sigf(fg) * c0v + sigf(ig) * tanhf(gg);                \
                float h = sigf(og) * tanhf(c);                                  \
                if (doclip) h = fminf(fmaxf(h, -20.f), 20.f);                   \
                (houtp)[(size_t)(rbase + r) * (ldhv) + uq] = f2bf(h);           \
            }                                                                   \
        }                                                                       \
    }

// ---------------------------------------------------------------------------
// prep device helpers
DEV void dev_cvt8(const float* src, int lds, unsigned short* dst, int ldd,
                  int c8, int bloc, int tid)
{
    size_t idx = (size_t)bloc * 256 + tid;
    size_t r = idx / c8, c = (idx % c8) * 8;
    const float* s = src + r * lds + c;
    float4 v0 = *(const float4*)s;
    float4 v1 = *(const float4*)(s + 4);
    ushort8 o;
    o[0] = f2bf(v0.x); o[1] = f2bf(v0.y); o[2] = f2bf(v0.z); o[3] = f2bf(v0.w);
    o[4] = f2bf(v1.x); o[5] = f2bf(v1.y); o[6] = f2bf(v1.z); o[7] = f2bf(v1.w);
    *(ushort8*)(dst + r * ldd + c) = o;
}

DEV void dev_cvtT(const float* src, int R, int C, int lds,
                  unsigned short* dst, int ldd, int mode, int bx, int by,
                  int tid, float* t /*32x33*/)
{
    const int x = tid & 31;
    for (int y = tid >> 5; y < 32; y += 8) {
        int r = by * 32 + y, c = bx * 32 + x;
        int scol = c;
        if (mode) scol = ((c >> 4) & 3) * 512 + (c >> 6) * 16 + (c & 15);
        t[y * 33 + x] = (r < R && c < C) ? src[(size_t)r * lds + scol] : 0.f;
    }
    __syncthreads();
    for (int y = tid >> 5; y < 32; y += 8) {
        int c = bx * 32 + y, r = by * 32 + x;
        if (c < C && r < R) dst[(size_t)c * ldd + r] = f2bf(t[x * 33 + y]);
    }
}

// ===========================================================================
// Dispatch 1 — k_prep
// ===========================================================================
__global__ __launch_bounds__(256) void k_prep(
    const float* __restrict__ X, const float* __restrict__ m0,
    const float* __restrict__ H0, const float* __restrict__ R0,
    const float* __restrict__ A0, const float* __restrict__ W_prep,
    const float* __restrict__ b_prep, const float* __restrict__ W_lstm,
    const float* __restrict__ b_r, const float* __restrict__ b_w,
    const float* __restrict__ W_ou, float* __restrict__ ws)
{
    __shared__ float sh[32 * 33 + 64];
    const int bid = blockIdx.x, tid = threadIdx.x;
    unsigned short* XHB  = (unsigned short*)(ws + OFF_XHB);
    unsigned short* W0T  = (unsigned short*)(ws + OFF_W0T);
    unsigned short* W1T  = (unsigned short*)(ws + OFF_W1T);
    unsigned short* WR2T = (unsigned short*)(ws + OFF_WR2T);
    unsigned short* M0B  = (unsigned short*)(ws + OFF_M0B);

    if (bid < P_M0) {
        dev_cvt8(X, 512, XHB, 1024, 64, bid - P_X0, tid);
    } else if (bid < P_W0) {
        dev_cvt8(m0, 128, M0B, 128, 16, bid - P_M0, tid);
    } else if (bid < P_W1) {
        int s = bid - P_W0;
        dev_cvtT(W_lstm, 512, 2048, 2048, W0T, 512, 1, s & 63, s >> 6, tid, sh);
    } else if (bid < P_WR2) {
        int s = bid - P_W1;
        dev_cvtT(W_lstm + (size_t)1536 * 2048, 1024, 2048, 2048, W1T, 1024, 1,
                 s & 63, s >> 6, tid, sh);
    } else if (bid < P_CA) {
        int s = bid - P_WR2;
        dev_cvtT(W_ou + (size_t)512 * 512, 256, 512, 512, WR2T, 256, 0,
                 s & 15, s >> 4, tid, sh);
    } else if (bid < P_ZC) {
        float* red = sh;
        for (int i = 0; i < 4; ++i) {
            float v = A0[i * 256 + tid];
            float mx = blk_reduce_max(v, red);
            float e = expf(v - mx);
            float s = blk_reduce_sum(e, red);
            ws[OFF_APREV + i * 256 + tid] = e / s;
        }
        float acc = 0.f;
        for (int m = 0; m < 128; ++m) {
            float t = m0[(size_t)tid * 128 + m];
            acc = fmaf(t, t, acc);
        }
        ws[OFF_MNORM + tid] = sqrtf(acc);
        for (int j = tid; j < 1152; j += 256)
            ws[OFF_BIASH + j] = (j < 268) ? b_r[j] : (j < 1048 ? b_w[j - 268] : 0.f);
    } else {
        // zpart layer 0
        int sub = bid - P_ZC;
        int colb = sub & 7, up = sub >> 3;
        int j = colb * 256 + tid;
        float acc = 0.f;
        if (up < 4) {
            sh[256 + tid] = tanhf(R0[tid]);
            __syncthreads();
            if (tid < 128) {
                int u = up * 128 + tid;
                float a = b_prep[u];
                for (int k = 0; k < 256; ++k)
                    a = fmaf(sh[256 + k], W_prep[(size_t)k * 512 + u], a);
                sh[tid] = a;
            }
            __syncthreads();
            const int u0 = up * 128;
            #pragma unroll 4
            for (int t = 0; t < 128; ++t)
                acc = fmaf(sh[t], W_lstm[(size_t)(512 + u0 + t) * 2048 + j], acc);
        } else {
            const int u0 = up * 128;
            #pragma unroll 4
            for (int t = 0; t < 128; ++t)
                acc = fmaf(H0[u0 - 512 + t],
                           W_lstm[(size_t)(512 + u0 + t) * 2048 + j], acc);
        }
        (ws + OFF_ZPART)[(size_t)up * 2048 + j] = acc;
    }
}

// ===========================================================================
// Dispatch 2 — k_mid: LSTM0 GEMM + ZX GEMM (L1 X-part) + pfold + late prep
// ===========================================================================
__global__ __launch_bounds__(256) void k_mid(
    const float* __restrict__ W_lstm, const float* __restrict__ W_r,
    const float* __restrict__ W_w, const float* __restrict__ W_ou,
    const float* __restrict__ H0, const float* __restrict__ b_lstm,
    const float* __restrict__ c0, float* __restrict__ ws)
{
    GEMM_SHARED
    const int s = blockIdx.x;
    float* sh = (float*)&As[0][0];   // alias for cvtT scratch
    unsigned short* XHB   = (unsigned short*)(ws + OFF_XHB);
    unsigned short* W0T   = (unsigned short*)(ws + OFF_W0T);
    unsigned short* W1T   = (unsigned short*)(ws + OFF_W1T);
    unsigned short* WRWT  = (unsigned short*)(ws + OFF_WRWT);
    unsigned short* WCOMB = (unsigned short*)(ws + OFF_WCOMB);
    unsigned short* WR2T  = (unsigned short*)(ws + OFF_WR2T);
    unsigned short* M0B   = (unsigned short*)(ws + OFF_M0B);
    unsigned short* ZX    = (unsigned short*)(ws + OFF_KMAT);
    const float* zpart    = ws + OFF_ZPART;

    if (s < M_WRr) {
        // ---- GEMM paths: LSTM0 / ZX / pfold ----
        const unsigned short *A, *Wt;
        int lda, ldw, row0, col0, Kr, mode;
        unsigned short* pCb = nullptr;
        if (s < M_ZX) {
            mode = 0;
            A = XHB;  lda = 1024; Wt = W0T; ldw = 512;
            row0 = (s & 31) * 64; col0 = (s >> 5) * 128; Kr = 512;
        } else if (s < M_PF) {
            int p = s - M_ZX;
            mode = 1;
            A = XHB;  lda = 1024; Wt = W1T; ldw = 1024;   // k 0..511 = X part
            row0 = (p & 31) * 64; col0 = (p >> 5) * 128; Kr = 512;
        } else {
            int p = s - M_PF;
            mode = 2;
            int pz = p >> 4, py = (p >> 3) & 1, px = p & 7;
            A = WR2T + pz * 128; lda = 256; Wt = M0B; ldw = 128;
            row0 = px * 64; col0 = py * 128; Kr = 128;
            pCb = WCOMB + 512 + pz * 256;
        }
        GEMM_REGS
        GEMM_MAINLOOP(Kr)
        if (mode == 0) {
            unsigned short* hout = XHB + 512;
            const unsigned short* zxn = nullptr;
            LSTM_EPILOGUE(0, 0, hout, 1024, zxn)
        } else if (mode == 1) {
            // ZX bf16 [2048][2048 permuted cols]
            #pragma unroll
            for (int i = 0; i < 2; ++i) {
                int m0r = row0 + wr * 32 + i * 16 + (lane >> 4) * 4;
                #pragma unroll
                for (int j = 0; j < 4; ++j) {
                    int n = col0 + wc * 64 + j * 16 + (lane & 15);
                    #pragma unroll
                    for (int r = 0; r < 4; ++r)
                        ZX[(size_t)(m0r + r) * 2048 + n] = f2bf(acc[i][j][r]);
                }
            }
        } else {
            #pragma unroll
            for (int i = 0; i < 2; ++i) {
                int m0r = row0 + wr * 32 + i * 16 + (lane >> 4) * 4;
                #pragma unroll
                for (int j = 0; j < 4; ++j) {
                    int n = col0 + wc * 64 + j * 16 + (lane & 15);
                    #pragma unroll
                    for (int r = 0; r < 4; ++r)
                        pCb[(size_t)(m0r + r) * 1024 + n] = f2bf(acc[i][j][r]);
                }
            }
        }
    } else if (s < M_WRw) {
        int s2 = s - M_WRr;
        dev_cvtT(W_r, 512, 268, 268, WRWT, 512, 0, s2 % 9, s2 / 9, threadIdx.x, sh);
    } else if (s < M_WOU) {
        int s3 = s - M_WRw;
        dev_cvtT(W_w, 512, 780, 780, WRWT + (size_t)268 * 512, 512, 0,
                 s3 % 25, s3 / 25, threadIdx.x, sh);
    } else if (s < M_ZC1) {
        int s4 = s - M_WOU;
        dev_cvtT(W_ou, 512, 512, 512, WCOMB, 1024, 0, s4 & 15, s4 >> 4,
                 threadIdx.x, sh);
    } else {
        // zpart layer 1 (H0 part only)
        int s5 = s - M_ZC1;
        int colb = s5 & 7, up = s5 >> 3;
        int j = colb * 256 + threadIdx.x;
        const int u0 = up * 64;
        const float* W1 = W_lstm + (size_t)1536 * 2048;
        float acc = 0.f;
        #pragma unroll 4
        for (int t = 0; t < 64; ++t)
            acc = fmaf(H0[512 + u0 + t], W1[(size_t)(1024 + u0 + t) * 2048 + j], acc);
        (ws + OFF_ZPART)[((size_t)8 + up) * 2048 + j] = acc;
    }
}

// ===========================================================================
// Dispatch 3 — LSTM layer 1: K=512 (h1 part) + ZX (X part) in epilogue
// ===========================================================================
__global__ __launch_bounds__(256) void gemm_lstm(
    const unsigned short* __restrict__ A, int lda,
    const unsigned short* __restrict__ Wt, int ldw,
    const float* __restrict__ zpart, const float* __restrict__ b_lstm,
    const float* __restrict__ c0, const unsigned short* __restrict__ ZXP,
    unsigned short* __restrict__ hout)
{
    GEMM_SHARED
    const int row0 = blockIdx.x * 64;
    const int col0 = blockIdx.y * 128;
    GEMM_REGS
    GEMM_MAINLOOP(512)
    LSTM_EPILOGUE(1, 1, hout, 1024, ZXP)
}

// ===========================================================================
// Dispatch 4 — k_heads: heads GEMM (f32+bias) + yh GEMM (out h-part, f32)
// ===========================================================================
__global__ __launch_bounds__(256) void k_heads(
    const unsigned short* __restrict__ HCAT,
    const unsigned short* __restrict__ WRWT,
    const unsigned short* __restrict__ WCOMB,
    const float* __restrict__ biash,
    float* __restrict__ heads, float* __restrict__ yh)
{
    GEMM_SHARED
    const int s = blockIdx.x;
    const unsigned short* A = HCAT;  const int lda = 1024;
    const unsigned short* Wt;
    int ldw, row0, col0;
    if (s < H_YH) {
        Wt = WRWT; ldw = 512;
        row0 = (s & 31) * 64; col0 = (s >> 5) * 128;
    } else {
        int p = s - H_YH;
        Wt = WCOMB; ldw = 1024;
        row0 = (p & 31) * 64; col0 = (p >> 5) * 128;
    }
    GEMM_REGS
    GEMM_MAINLOOP(512)
    if (s < H_YH) {
        #pragma unroll
        for (int i = 0; i < 2; ++i) {
            int m0r = row0 + wr * 32 + i * 16 + (lane >> 4) * 4;
            #pragma unroll
            for (int j = 0; j < 4; ++j) {
                int n = col0 + wc * 64 + j * 16 + (lane & 15);
                if (n >= 1048) continue;
                float bv = biash[n];
                #pragma unroll
                for (int r = 0; r < 4; ++r)
                    heads[(size_t)(m0r + r) * 1048 + n] = acc[i][j][r] + bv;
            }
        }
    } else {
        #pragma unroll
        for (int i = 0; i < 2; ++i) {
            int m0r = row0 + wr * 32 + i * 16 + (lane >> 4) * 4;
            #pragma unroll
            for (int j = 0; j < 4; ++j) {
                int n = col0 + wc * 64 + j * 16 + (lane & 15);
                #pragma unroll
                for (int r = 0; r < 4; ++r)
                    yh[(size_t)(m0r + r) * 512 + n] = acc[i][j][r];
            }
        }
    }
}

// ===========================================================================
// Dispatch 5 — kmat GEMM with fused tanh k-prep
// ===========================================================================
__global__ __launch_bounds__(256) void gemm_kmat(
    const float* __restrict__ heads,
    const unsigned short* __restrict__ M0B,
    float* __restrict__ C)
{
    GEMM_SHARED
    const int row0 = blockIdx.x * 64;
    const int col0 = blockIdx.y * 128;
    GEMM_REGS

#define KMAT_STAGE(buf, k0)                                                     \
    {                                                                           \
        _Pragma("unroll")                                                       \
        for (int q = 0; q < 2; ++q) {                                           \
            int R = row0 + q * 32 + (tid >> 3);                                 \
            int b = R >> 2, ih = R & 3;                                         \
            int cb = (ih < 2) ? ih * 134 : 268 + (ih - 2) * 390;                \
            const float* hp = heads + (size_t)b * 1048 + cb + (k0) + ke;        \
            ushort8 o;                                                          \
            _Pragma("unroll")                                                   \
            for (int j = 0; j < 8; ++j) o[j] = f2bf(tanhf(hp[j]));              \
            *(ushort8*)&As[buf][q * 2048 + tid * 8] = o;                        \
        }                                                                       \
        _Pragma("unroll")                                                       \
        for (int q = 0; q < 4; ++q)                                             \
            gload16(M0B + (size_t)(col0 + q * 32 + (tid >> 3)) * 128 + (k0) + ke,\
                    &Ws[buf][q * 2048 + tid * 8]);                              \
    }

    int cur = 0;
    KMAT_STAGE(0, 0);
    for (int t = 0; t < 2; ++t) {
        __syncthreads();
        if (t == 0) KMAT_STAGE(1, 64);
        GEMM_FRAGS_AND_MFMA(As[cur], Ws[cur]);
        cur ^= 1;
    }
#undef KMAT_STAGE
    #pragma unroll
    for (int i = 0; i < 2; ++i) {
        int m0r = row0 + wr * 32 + i * 16 + (lane >> 4) * 4;
        #pragma unroll
        for (int j = 0; j < 4; ++j) {
            int n = col0 + wc * 64 + j * 16 + (lane & 15);
            #pragma unroll
            for (int r = 0; r < 4; ++r)
                C[(size_t)(m0r + r) * 256 + n] = acc[i][j][r];
        }
    }
}

// ===========================================================================
// Dispatch 6 — addressing (4 heads, shuffle reductions)
// ===========================================================================
__global__ __launch_bounds__(256) void k_addr(
    const float* __restrict__ heads, const float* __restrict__ kmat,
    const float* __restrict__ mnorm, const float* __restrict__ aprev,
    float* __restrict__ at, unsigned short* __restrict__ hcat,
    float* __restrict__ era, float* __restrict__ addv)
{
    __shared__ float red4[4];
    __shared__ float wgs[256];
    __shared__ float sc[6];
    const int b = blockIdx.x, i = blockIdx.y, tid = threadIdx.x;
    const int cb = (i < 2) ? i * 134 : 268 + (i - 2) * 390;
    const float* hd = heads + (size_t)b * 1048 + cb;
    float kv = (tid < 128) ? tanhf(hd[tid]) : 0.f;
    float kn = sqrtf(blk_sum4(kv * kv, red4));
    if (i >= 2 && tid < 128) {
        era [((size_t)b * 2 + (i - 2)) * 128 + tid] = sigf(hd[134 + tid]);
        addv[((size_t)b * 2 + (i - 2)) * 128 + tid] = tanhf(hd[262 + tid]);
    }
    if (tid == 0) {
        sc[0] = softplusf(hd[128]);
        sc[1] = sigf(hd[129]);
        float v0 = hd[130], v1 = hd[131], v2 = hd[132];
        float mx = fmaxf(v0, fmaxf(v1, v2));
        float e0 = expf(v0 - mx), e1 = expf(v1 - mx), e2 = expf(v2 - mx);
        float ssum = e0 + e1 + e2;
        sc[2] = e0 / ssum; sc[3] = e1 / ssum; sc[4] = e2 / ssum;
        sc[5] = softplusf(hd[133]);
    }
    __syncthreads();
    const float beta = sc[0], g = sc[1], s0 = sc[2], s1 = sc[3], s2 = sc[4],
                gamma = sc[5];
    float inner = kmat[((size_t)b * 4 + i) * 256 + tid];
    float K = inner / (kn * mnorm[tid] + 1e-8f);
    float x = beta * K;
    float mx = blk_max4(x, red4);
    float e = expf(x - mx);
    float se = blk_sum4(e, red4);
    float wc = e / se;
    float wg = g * wc + (1.f - g) * aprev[i * 256 + tid];
    wgs[tid] = wg;
    __syncthreads();
    float wconv = s0 * wg + s1 * wgs[(tid + 255) & 255] + s2 * wgs[(tid + 1) & 255];
    float wsh = powf(wconv, gamma);
    float ssum = blk_sum4(wsh, red4);
    float w = wsh / ssum;
    if (i < 2) hcat[(size_t)b * 1024 + 512 + i * 256 + tid] = f2bf(w);
    else       at[((size_t)(i - 2) * Bn + b) * 256 + tid] = w;
}

// ===========================================================================
// Dispatch 7 — k_tail: out GEMM (K=512 A-part + yh base + clip) + memt.
// ===========================================================================
__global__ __launch_bounds__(256) void k_tail(
    const unsigned short* __restrict__ HCAT,
    const unsigned short* __restrict__ WCOMB,
    const float* __restrict__ yh, const float* __restrict__ b_ou,
    const float* __restrict__ m0, const float* __restrict__ at,
    const float* __restrict__ era, const float* __restrict__ addv,
    float* __restrict__ out)
{
    GEMM_SHARED
    const int s = blockIdx.x;
    if (s < T_MEM) {
        // ---- out GEMM: y = clip(yh + A-cols @ WCOMB[k 512:] + b_ou) ----
        const unsigned short* A  = HCAT + 512;        const int lda = 1024;
        const unsigned short* Wt = WCOMB + 512;       const int ldw = 1024;
        const int row0 = (s & 31) * 64;
        const int col0 = (s >> 5) * 128;
        GEMM_REGS
        GEMM_MAINLOOP(512)
        #pragma unroll
        for (int i = 0; i < 2; ++i) {
            int m0r = row0 + wr * 32 + i * 16 + (lane >> 4) * 4;
            #pragma unroll
            for (int j = 0; j < 4; ++j) {
                int n = col0 + wc * 64 + j * 16 + (lane & 15);
                if (n >= 512) continue;
                float bv = b_ou[n];
                #pragma unroll
                for (int r = 0; r < 4; ++r) {
                    float v = acc[i][j][r] + bv + yh[(size_t)(m0r + r) * 512 + n];
                    out[(size_t)(m0r + r) * 512 + n] = fminf(fmaxf(v, -20.f), 20.f);
                }
            }
        }
    } else {
        // ---- memt: 8 batch rows per block, m0 reused 8x, NT stores ----
        const int tid = threadIdx.x;
        const int b0 = (s - T_MEM) * 8;
        float (*at_s)[8][256] = (float(*)[8][256])(&As[0][0]);     // 16 KB
        float (*er_s)[8][128] = (float(*)[8][128])(&Ws[0][0]);     // 8 KB
        float (*ad_s)[8][128] = (float(*)[8][128])(&Ws[0][4096]);  // 8 KB
        for (int t = tid; t < 1024; t += 256) {
            int i = t >> 9, rem = t & 511;
            int bb = rem >> 6, n4 = rem & 63;
            ((float4*)&at_s[i][bb][0])[n4] =
                ((const float4*)(at + ((size_t)i * Bn + b0 + bb) * 256))[n4];
        }
        for (int t = tid; t < 512; t += 256) {
            int i = t >> 8, rem = t & 255;
            int bb = rem >> 5, m4 = rem & 31;
            ((float4*)&er_s[i][bb][0])[m4] =
                ((const float4*)(era + ((size_t)(b0 + bb) * 2 + i) * 128))[m4];
            ((float4*)&ad_s[i][bb][0])[m4] =
                ((const float4*)(addv + ((size_t)(b0 + bb) * 2 + i) * 128))[m4];
        }
        __syncthreads();
        const float4* m0v = (const float4*)m0;
        float4* outv = (float4*)(out + (size_t)Bn * Un);
        for (int pos = tid; pos < 8192; pos += 256) {
            int mq = pos & 31, n = pos >> 5;
            float4 t0 = m0v[pos];
            #pragma unroll
            for (int bb = 0; bb < 8; ++bb) {
                float w0 = at_s[0][bb][n], w1 = at_s[1][bb][n];
                float4 e0 = *(const float4*)&er_s[0][bb][mq * 4];
                float4 a0 = *(const float4*)&ad_s[0][bb][mq * 4];
                float4 e1 = *(const float4*)&er_s[1][bb][mq * 4];
                float4 a1 = *(const float4*)&ad_s[1][bb][mq * 4];
                float4 t = t0;
#define UPD(c) { t.c = t.c * (1.f - w0 * e0.c) + w0 * a0.c; \
                 t.c = t.c * (1.f - w1 * e1.c) + w1 * a1.c; }
                UPD(x) UPD(y) UPD(z) UPD(w)
#undef UPD
                __builtin_nontemporal_store(*(f32x4*)&t,
                    (f32x4*)&outv[(size_t)(b0 + bb) * 8192 + pos]);
            }
        }
    }
}

extern "C" void kernel_launch(void* const* d_in, const int* in_sizes, int n_in,
                              void* d_out, int out_size, void* d_ws, size_t ws_size,
                              hipStream_t stream)
{
    const float* X      = (const float*)d_in[0];
    const float* m0     = (const float*)d_in[1];
    const float* H0     = (const float*)d_in[2];
    const float* C0     = (const float*)d_in[3];
    const float* R0     = (const float*)d_in[4];
    const float* A0     = (const float*)d_in[5];
    const float* W_prep = (const float*)d_in[6];
    const float* b_prep = (const float*)d_in[7];
    const float* W_lstm = (const float*)d_in[8];
    const float* b_lstm = (const float*)d_in[9];
    const float* W_r    = (const float*)d_in[10];
    const float* b_r    = (const float*)d_in[11];
    const float* W_w    = (const float*)d_in[12];
    const float* b_w    = (const float*)d_in[13];
    const float* W_ou   = (const float*)d_in[14];
    const float* b_ou   = (const float*)d_in[15];
    float* ws  = (float*)d_ws;
    float* out = (float*)d_out;

    unsigned short* XHB   = (unsigned short*)(ws + OFF_XHB);
    unsigned short* HCAT  = (unsigned short*)(ws + OFF_HCAT);
    unsigned short* W1T   = (unsigned short*)(ws + OFF_W1T);
    unsigned short* WRWT  = (unsigned short*)(ws + OFF_WRWT);
    unsigned short* WCOMB = (unsigned short*)(ws + OFF_WCOMB);
    unsigned short* M0B   = (unsigned short*)(ws + OFF_M0B);
    unsigned short* ZX    = (unsigned short*)(ws + OFF_KMAT);

    // 1. critical prep
    k_prep<<<P_END, 256, 0, stream>>>(
        X, m0, H0, R0, A0, W_prep, b_prep, W_lstm, b_r, b_w, W_ou, ws);

    // 2. LSTM0 + ZX (L1 X-part) + pfold + late prep (concurrent)
    k_mid<<<M_END, 256, 0, stream>>>(
        W_lstm, W_r, W_w, W_ou, H0, b_lstm, C0, ws);

    // 3. LSTM layer 1 (K=512 h1-part; ZX added in epilogue)
    gemm_lstm<<<dim3(32, 16), 256, 0, stream>>>(
        XHB + 512, 1024, W1T + 512, 1024, ws + OFF_ZPART, b_lstm, C0, ZX, HCAT);

    // 4. heads + yh (out h-part)
    k_heads<<<H_END, 256, 0, stream>>>(
        HCAT, WRWT, WCOMB, ws + OFF_BIASH, ws + OFF_HEADS, ws + OFF_YH);

    // 5. kmat (fused tanh)
    gemm_kmat<<<dim3(128, 2), 256, 0, stream>>>(
        ws + OFF_HEADS, M0B, ws + OFF_KMAT);

    // 6. addressing
    k_addr<<<dim3(Bn, 4), 256, 0, stream>>>(
        ws + OFF_HEADS, ws + OFF_KMAT, ws + OFF_MNORM, ws + OFF_APREV,
        ws + OFF_AT, HCAT, ws + OFF_ERA, ws + OFF_ADD);

    // 7. out GEMM (K=512 + yh) + memt (overlapped)
    k_tail<<<T_END, 256, 0, stream>>>(
        HCAT, WCOMB, ws + OFF_YH, b_ou, m0, ws + OFF_AT, ws + OFF_ERA,
        ws + OFF_ADD, out);
}

// Round 14
// 166.506 us; speedup vs baseline: 1.1893x; 1.0417x over previous
//
#include <hip/hip_runtime.h>
#include <math.h>

static constexpr int Bn = 2048;   // batch
static constexpr int Nn = 256;    // memory locations
static constexpr int Mn = 128;    // memory width
static constexpr int Un = 512;    // units

// Workspace layout (f32 offsets)
static constexpr size_t OFF_MNORM = 4608;     // 256
static constexpr size_t OFF_APREV = 4864;     // 1024
static constexpr size_t OFF_BIASH = 5888;     // 1152
static constexpr size_t OFF_KMAT  = 16384;                           // f32 [4][2048][256]; doubles as ZX bf16 [2048][2048]
static constexpr size_t OFF_HEADS = OFF_KMAT + 2097152;              // f32 [2048][1048]
static constexpr size_t OFF_AT    = OFF_HEADS + 2146304;             // f32 [2][2048][256]
static constexpr size_t OFF_ERA   = OFF_AT + 1048576;                // f32 [2048][2][128]
static constexpr size_t OFF_ADD   = OFF_ERA + 524288;
static constexpr size_t OFF_XHB   = OFF_ADD + 524288;                // bf16 [2048][1024]
static constexpr size_t OFF_HCAT  = OFF_XHB + 1048576;               // bf16 [2048][1024]
static constexpr size_t OFF_W0T   = OFF_HCAT + 1048576;              // bf16 [2048][512]
static constexpr size_t OFF_W1T   = OFF_W0T + 524288;                // bf16 [2048][1024]
static constexpr size_t OFF_WRWT  = OFF_W1T + 1048576;               // bf16 [1152][512]
static constexpr size_t OFF_WCOMB = OFF_WRWT + 294912;               // bf16 [512][1024]
static constexpr size_t OFF_WR2T  = OFF_WCOMB + 262144;              // bf16 [512][256]
static constexpr size_t OFF_M0B   = OFF_WR2T + 65536;                // bf16 [256][128]
static constexpr size_t OFF_ZPART = OFF_M0B + 16384;                 // f32 [2][8][2048]
static constexpr size_t OFF_YH    = OFF_ZPART + 32768;               // f32 [2048][512]

// k_prep (dispatch 1) block table
static constexpr int P_X0  = 0;            // cvt8 X        (512)
static constexpr int P_M0  = 512;          // cvt8 m0       (16)
static constexpr int P_W0  = 528;          // cvtT W0 gate  (64x16)
static constexpr int P_W1  = 1552;         // cvtT W1 gate  (64x32)
static constexpr int P_WR2 = 3600;         // cvtT W_ou r   (16x8)
static constexpr int P_CA  = 3728;         // const-a       (1)
static constexpr int P_ZC  = 3729;         // zpart L0      (64)
static constexpr int P_END = 3793;

// k_mid (dispatch 2) block table
static constexpr int M_L0  = 0;            // LSTM0 GEMM    (512)
static constexpr int M_ZX  = 512;          // ZX GEMM       (512)
static constexpr int M_PF  = 1024;         // pfold         (32)
static constexpr int M_WRr = 1056;         // cvtT W_r      (144)
static constexpr int M_WRw = 1200;         // cvtT W_w      (400)
static constexpr int M_WOU = 1600;         // cvtT W_ou h   (256)
static constexpr int M_ZC1 = 1856;         // zpart L1      (64)
static constexpr int M_END = 1920;

// k_hk (dispatch 4: heads + yh + fused kmat) block table
static constexpr int H_HD  = 0;            // heads GEMM    (288 = 32x9)
static constexpr int H_YH  = 288;          // yh GEMM       (128 = 32x4)
static constexpr int H_KM  = 416;          // kmat2         (256 = 4i x 32bt x 2nt)
static constexpr int H_END = 672;

// k_tail (dispatch 6) block table
static constexpr int T_OUT = 0;            // out GEMM K=512 (128)
static constexpr int T_MEM = 128;          // memt          (256)
static constexpr int T_END = 384;

#define DEV __device__ __forceinline__

typedef __attribute__((ext_vector_type(8))) short bf16x8;
typedef __attribute__((ext_vector_type(4))) float f32x4;
typedef __attribute__((ext_vector_type(8))) unsigned short ushort8;
typedef unsigned int u32;

DEV float sigf(float x) { return 1.0f / (1.0f + expf(-x)); }
DEV float softplusf(float x) { return x > 20.0f ? x : log1pf(expf(x)); }
DEV unsigned short f2bf(float f) {   // RNE float->bf16
    unsigned u = __float_as_uint(f);
    u = (u + 0x7FFFu + ((u >> 16) & 1u)) >> 16;
    return (unsigned short)u;
}
DEV float b2f(unsigned short u) { return __uint_as_float((u32)u << 16); }
DEV void gload16(const unsigned short* g, unsigned short* l) {
    __builtin_amdgcn_global_load_lds(
        (const __attribute__((address_space(1))) u32*)g,
        (__attribute__((address_space(3))) u32*)l, 16, 0, 0);
}

// tree reductions (k_prep const block only)
DEV float blk_reduce_max(float v, float* red) {
    int tid = threadIdx.x;
    red[tid] = v; __syncthreads();
    for (int s = (int)blockDim.x >> 1; s > 0; s >>= 1) {
        if (tid < s) red[tid] = fmaxf(red[tid], red[tid + s]);
        __syncthreads();
    }
    float r = red[0]; __syncthreads();
    return r;
}
DEV float blk_reduce_sum(float v, float* red) {
    int tid = threadIdx.x;
    red[tid] = v; __syncthreads();
    for (int s = (int)blockDim.x >> 1; s > 0; s >>= 1) {
        if (tid < s) red[tid] += red[tid + s];
        __syncthreads();
    }
    float r = red[0]; __syncthreads();
    return r;
}

// wave-shuffle reductions for 256-thread blocks
DEV float wv_sum(float v) {
    #pragma unroll
    for (int off = 32; off; off >>= 1) v += __shfl_xor(v, off);
    return v;
}
DEV float wv_max(float v) {
    #pragma unroll
    for (int off = 32; off; off >>= 1) v = fmaxf(v, __shfl_xor(v, off));
    return v;
}
DEV float blk_sum4(float v, float* red4) {
    v = wv_sum(v);
    int w = threadIdx.x >> 6;
    if ((threadIdx.x & 63) == 0) red4[w] = v;
    __syncthreads();
    float r = red4[0] + red4[1] + red4[2] + red4[3];
    __syncthreads();
    return r;
}
DEV float blk_max4(float v, float* red4) {
    v = wv_max(v);
    int w = threadIdx.x >> 6;
    if ((threadIdx.x & 63) == 0) red4[w] = v;
    __syncthreads();
    float r = fmaxf(fmaxf(red4[0], red4[1]), fmaxf(red4[2], red4[3]));
    __syncthreads();
    return r;
}

// ===========================================================================
// GEMM machinery: 64x128 tile, 4 waves (2x2), BK=64, dbuf LDS via
// global_load_lds (16B), XOR-swizzle via pre-swizzled source k-offset,
// T4 counted-vmcnt mainloop. (R11 configuration — empirically best.)
// ===========================================================================
#define GEMM_SHARED                                                             \
    __shared__ __align__(16) unsigned short As[2][64 * 64];                     \
    __shared__ __align__(16) unsigned short Ws[2][128 * 64];

#define GEMM_REGS                                                               \
    const int tid  = threadIdx.x;                                               \
    const int lane = tid & 63;                                                  \
    const int wave = tid >> 6;                                                  \
    const int wr = wave >> 1, wc = wave & 1;                                    \
    const int ke = ((tid & 7) * 8) ^ (((tid >> 3) & 7) << 3);                   \
    const int frow = lane & 15;                                                 \
    const int fko  = (lane >> 4) * 8;                                           \
    const int fxm  = (frow & 7) << 3;                                           \
    f32x4 acc[2][4];                                                            \
    _Pragma("unroll")                                                           \
    for (int i = 0; i < 2; ++i)                                                 \
        _Pragma("unroll")                                                       \
        for (int j = 0; j < 4; ++j) acc[i][j] = (f32x4){0.f, 0.f, 0.f, 0.f};

#define GEMM_STAGE(buf, k0)                                                     \
    {                                                                           \
        _Pragma("unroll")                                                       \
        for (int q = 0; q < 2; ++q)                                             \
            gload16(A  + (size_t)(row0 + q * 32 + (tid >> 3)) * lda + (k0) + ke,\
                    &As[buf][q * 2048 + tid * 8]);                              \
        _Pragma("unroll")                                                       \
        for (int q = 0; q < 4; ++q)                                             \
            gload16(Wt + (size_t)(col0 + q * 32 + (tid >> 3)) * ldw + (k0) + ke,\
                    &Ws[buf][q * 2048 + tid * 8]);                              \
    }

#define GEMM_FRAGS_AND_MFMA(Ab, Wb)                                             \
    {                                                                           \
        bf16x8 af[2][2], wf[2][4];                                              \
        _Pragma("unroll")                                                       \
        for (int kk = 0; kk < 2; ++kk) {                                        \
            _Pragma("unroll")                                                   \
            for (int i = 0; i < 2; ++i) {                                       \
                int fr = wr * 32 + i * 16 + frow;                               \
                af[kk][i] = *(const bf16x8*)&(Ab)[fr * 64 + ((kk * 32 + fko) ^ fxm)]; \
            }                                                                   \
            _Pragma("unroll")                                                   \
            for (int j = 0; j < 4; ++j) {                                       \
                int fr = wc * 64 + j * 16 + frow;                               \
                wf[kk][j] = *(const bf16x8*)&(Wb)[fr * 64 + ((kk * 32 + fko) ^ fxm)]; \
            }                                                                   \
        }                                                                       \
        __builtin_amdgcn_s_setprio(1);                                          \
        _Pragma("unroll")                                                       \
        for (int kk = 0; kk < 2; ++kk)                                          \
            _Pragma("unroll")                                                   \
            for (int i = 0; i < 2; ++i)                                         \
                _Pragma("unroll")                                               \
                for (int j = 0; j < 4; ++j)                                     \
                    acc[i][j] = __builtin_amdgcn_mfma_f32_16x16x32_bf16(        \
                        af[kk][i], wf[kk][j], acc[i][j], 0, 0, 0);              \
        __builtin_amdgcn_s_setprio(0);                                          \
    }

#define GEMM_MAINLOOP(Kr)                                                       \
    {                                                                           \
        const int nt = (Kr) >> 6;                                               \
        int cur = 0;                                                            \
        GEMM_STAGE(0, 0);                                                       \
        for (int t = 0; t < nt; ++t) {                                          \
            if (t + 1 < nt) {                                                   \
                GEMM_STAGE(cur ^ 1, (t + 1) * 64);                              \
                asm volatile("s_waitcnt vmcnt(6)" ::: "memory");                \
            } else {                                                            \
                asm volatile("s_waitcnt vmcnt(0)" ::: "memory");                \
            }                                                                   \
            __builtin_amdgcn_sched_barrier(0);                                  \
            __builtin_amdgcn_s_barrier();                                       \
            __builtin_amdgcn_sched_barrier(0);                                  \
            GEMM_FRAGS_AND_MFMA(As[cur], Ws[cur]);                              \
            __builtin_amdgcn_sched_barrier(0);                                  \
            __builtin_amdgcn_s_barrier();                                       \
            cur ^= 1;                                                           \
        }                                                                       \
    }

// LSTM epilogue: gate-permuted cols, fused split-K zc reduce + optional ZX
// (bf16 [row][2048 permuted cols]) + cell nonlinearity.
#define LSTM_EPILOGUE(zc, doclip, houtp, ldhv, ZXP)                             \
    {                                                                           \
        const int uu = lane & 15;                                               \
        const int q  = (col0 >> 6) + wc;                                        \
        const int uq = q * 16 + uu;                                             \
        const float c0v = c0[(zc) * 512 + uq];                                  \
        float bg[4];                                                            \
        _Pragma("unroll")                                                       \
        for (int g = 0; g < 4; ++g) {                                           \
            int j = g * 512 + q * 16 + uu;                                      \
            float a = b_lstm[(zc) * 2048 + j];                                  \
            _Pragma("unroll")                                                   \
            for (int p = 0; p < 8; ++p)                                         \
                a += zpart[((size_t)(zc) * 8 + p) * 2048 + j];                  \
            bg[g] = a;                                                          \
        }                                                                       \
        _Pragma("unroll")                                                       \
        for (int i = 0; i < 2; ++i) {                                           \
            int rbase = row0 + wr * 32 + i * 16 + (lane >> 4) * 4;              \
            _Pragma("unroll")                                                   \
            for (int r = 0; r < 4; ++r) {                                       \
                float z0 = 0.f, z1 = 0.f, z2 = 0.f, z3 = 0.f;                   \
                if (ZXP) {                                                      \
                    const unsigned short* zr = (ZXP) +                          \
                        (size_t)(rbase + r) * 2048 + q * 64 + uu;               \
                    z0 = b2f(zr[0]);  z1 = b2f(zr[16]);                         \
                    z2 = b2f(zr[32]); z3 = b2f(zr[48]);                         \
                }                                                               \
                float ig = acc[i][0][r] + bg[0] + z0;                           \
                float fg = acc[i][1][r] + bg[1] + z1;                           \
                float gg = acc[i][2][r] + bg[2] + z2;                           \
                float og = acc[i][3][r] + bg[3] + z3;                           \
                float c = sigf(fg) * c0v + sigf(ig) * tanhf(gg);                \
                float h = sigf(og) * tanhf(c);                                  \
                if (doclip) h = fminf(fmaxf(h, -20.f), 20.f);                   \
                (houtp)[(size_t)(rbase + r) * (ldhv) + uq] = f2bf(h);           \
            }                                                                   \
        }                                                                       \
    }

// ---------------------------------------------------------------------------
// prep device helpers
DEV void dev_cvt8(const float* src, int lds, unsigned short* dst, int ldd,
                  int c8, int bloc, int tid)
{
    size_t idx = (size_t)bloc * 256 + tid;
    size_t r = idx / c8, c = (idx % c8) * 8;
    const float* s = src + r * lds + c;
    float4 v0 = *(const float4*)s;
    float4 v1 = *(const float4*)(s + 4);
    ushort8 o;
    o[0] = f2bf(v0.x); o[1] = f2bf(v0.y); o[2] = f2bf(v0.z); o[3] = f2bf(v0.w);
    o[4] = f2bf(v1.x); o[5] = f2bf(v1.y); o[6] = f2bf(v1.z); o[7] = f2bf(v1.w);
    *(ushort8*)(dst + r * ldd + c) = o;
}

DEV void dev_cvtT(const float* src, int R, int C, int lds,
                  unsigned short* dst, int ldd, int mode, int bx, int by,
                  int tid, float* t /*32x33*/)
{
    const int x = tid & 31;
    for (int y = tid >> 5; y < 32; y += 8) {
        int r = by * 32 + y, c = bx * 32 + x;
        int scol = c;
        if (mode) scol = ((c >> 4) & 3) * 512 + (c >> 6) * 16 + (c & 15);
        t[y * 33 + x] = (r < R && c < C) ? src[(size_t)r * lds + scol] : 0.f;
    }
    __syncthreads();
    for (int y = tid >> 5; y < 32; y += 8) {
        int c = bx * 32 + y, r = by * 32 + x;
        if (c < C && r < R) dst[(size_t)c * ldd + r] = f2bf(t[x * 33 + y]);
    }
}

// ===========================================================================
// Dispatch 1 — k_prep
// ===========================================================================
__global__ __launch_bounds__(256) void k_prep(
    const float* __restrict__ X, const float* __restrict__ m0,
    const float* __restrict__ H0, const float* __restrict__ R0,
    const float* __restrict__ A0, const float* __restrict__ W_prep,
    const float* __restrict__ b_prep, const float* __restrict__ W_lstm,
    const float* __restrict__ b_r, const float* __restrict__ b_w,
    const float* __restrict__ W_ou, float* __restrict__ ws)
{
    __shared__ float sh[32 * 33 + 64];
    const int bid = blockIdx.x, tid = threadIdx.x;
    unsigned short* XHB  = (unsigned short*)(ws + OFF_XHB);
    unsigned short* W0T  = (unsigned short*)(ws + OFF_W0T);
    unsigned short* W1T  = (unsigned short*)(ws + OFF_W1T);
    unsigned short* WR2T = (unsigned short*)(ws + OFF_WR2T);
    unsigned short* M0B  = (unsigned short*)(ws + OFF_M0B);

    if (bid < P_M0) {
        dev_cvt8(X, 512, XHB, 1024, 64, bid - P_X0, tid);
    } else if (bid < P_W0) {
        dev_cvt8(m0, 128, M0B, 128, 16, bid - P_M0, tid);
    } else if (bid < P_W1) {
        int s = bid - P_W0;
        dev_cvtT(W_lstm, 512, 2048, 2048, W0T, 512, 1, s & 63, s >> 6, tid, sh);
    } else if (bid < P_WR2) {
        int s = bid - P_W1;
        dev_cvtT(W_lstm + (size_t)1536 * 2048, 1024, 2048, 2048, W1T, 1024, 1,
                 s & 63, s >> 6, tid, sh);
    } else if (bid < P_CA) {
        int s = bid - P_WR2;
        dev_cvtT(W_ou + (size_t)512 * 512, 256, 512, 512, WR2T, 256, 0,
                 s & 15, s >> 4, tid, sh);
    } else if (bid < P_ZC) {
        float* red = sh;
        for (int i = 0; i < 4; ++i) {
            float v = A0[i * 256 + tid];
            float mx = blk_reduce_max(v, red);
            float e = expf(v - mx);
            float s = blk_reduce_sum(e, red);
            ws[OFF_APREV + i * 256 + tid] = e / s;
        }
        float acc = 0.f;
        for (int m = 0; m < 128; ++m) {
            float t = m0[(size_t)tid * 128 + m];
            acc = fmaf(t, t, acc);
        }
        ws[OFF_MNORM + tid] = sqrtf(acc);
        for (int j = tid; j < 1152; j += 256)
            ws[OFF_BIASH + j] = (j < 268) ? b_r[j] : (j < 1048 ? b_w[j - 268] : 0.f);
    } else {
        // zpart layer 0
        int sub = bid - P_ZC;
        int colb = sub & 7, up = sub >> 3;
        int j = colb * 256 + tid;
        float acc = 0.f;
        if (up < 4) {
            sh[256 + tid] = tanhf(R0[tid]);
            __syncthreads();
            if (tid < 128) {
                int u = up * 128 + tid;
                float a = b_prep[u];
                for (int k = 0; k < 256; ++k)
                    a = fmaf(sh[256 + k], W_prep[(size_t)k * 512 + u], a);
                sh[tid] = a;
            }
            __syncthreads();
            const int u0 = up * 128;
            #pragma unroll 4
            for (int t = 0; t < 128; ++t)
                acc = fmaf(sh[t], W_lstm[(size_t)(512 + u0 + t) * 2048 + j], acc);
        } else {
            const int u0 = up * 128;
            #pragma unroll 4
            for (int t = 0; t < 128; ++t)
                acc = fmaf(H0[u0 - 512 + t],
                           W_lstm[(size_t)(512 + u0 + t) * 2048 + j], acc);
        }
        (ws + OFF_ZPART)[(size_t)up * 2048 + j] = acc;
    }
}

// ===========================================================================
// Dispatch 2 — k_mid: LSTM0 GEMM + ZX GEMM (L1 X-part) + pfold + late prep
// ===========================================================================
__global__ __launch_bounds__(256) void k_mid(
    const float* __restrict__ W_lstm, const float* __restrict__ W_r,
    const float* __restrict__ W_w, const float* __restrict__ W_ou,
    const float* __restrict__ H0, const float* __restrict__ b_lstm,
    const float* __restrict__ c0, float* __restrict__ ws)
{
    GEMM_SHARED
    const int s = blockIdx.x;
    float* sh = (float*)&As[0][0];   // alias for cvtT scratch
    unsigned short* XHB   = (unsigned short*)(ws + OFF_XHB);
    unsigned short* W0T   = (unsigned short*)(ws + OFF_W0T);
    unsigned short* W1T   = (unsigned short*)(ws + OFF_W1T);
    unsigned short* WRWT  = (unsigned short*)(ws + OFF_WRWT);
    unsigned short* WCOMB = (unsigned short*)(ws + OFF_WCOMB);
    unsigned short* WR2T  = (unsigned short*)(ws + OFF_WR2T);
    unsigned short* M0B   = (unsigned short*)(ws + OFF_M0B);
    unsigned short* ZX    = (unsigned short*)(ws + OFF_KMAT);
    const float* zpart    = ws + OFF_ZPART;

    if (s < M_WRr) {
        // ---- GEMM paths: LSTM0 / ZX / pfold ----
        const unsigned short *A, *Wt;
        int lda, ldw, row0, col0, Kr, mode;
        unsigned short* pCb = nullptr;
        if (s < M_ZX) {
            mode = 0;
            A = XHB;  lda = 1024; Wt = W0T; ldw = 512;
            row0 = (s & 31) * 64; col0 = (s >> 5) * 128; Kr = 512;
        } else if (s < M_PF) {
            int p = s - M_ZX;
            mode = 1;
            A = XHB;  lda = 1024; Wt = W1T; ldw = 1024;   // k 0..511 = X part
            row0 = (p & 31) * 64; col0 = (p >> 5) * 128; Kr = 512;
        } else {
            int p = s - M_PF;
            mode = 2;
            int pz = p >> 4, py = (p >> 3) & 1, px = p & 7;
            A = WR2T + pz * 128; lda = 256; Wt = M0B; ldw = 128;
            row0 = px * 64; col0 = py * 128; Kr = 128;
            pCb = WCOMB + 512 + pz * 256;
        }
        GEMM_REGS
        GEMM_MAINLOOP(Kr)
        if (mode == 0) {
            unsigned short* hout = XHB + 512;
            const unsigned short* zxn = nullptr;
            LSTM_EPILOGUE(0, 0, hout, 1024, zxn)
        } else if (mode == 1) {
            // ZX bf16 [2048][2048 permuted cols]
            #pragma unroll
            for (int i = 0; i < 2; ++i) {
                int m0r = row0 + wr * 32 + i * 16 + (lane >> 4) * 4;
                #pragma unroll
                for (int j = 0; j < 4; ++j) {
                    int n = col0 + wc * 64 + j * 16 + (lane & 15);
                    #pragma unroll
                    for (int r = 0; r < 4; ++r)
                        ZX[(size_t)(m0r + r) * 2048 + n] = f2bf(acc[i][j][r]);
                }
            }
        } else {
            #pragma unroll
            for (int i = 0; i < 2; ++i) {
                int m0r = row0 + wr * 32 + i * 16 + (lane >> 4) * 4;
                #pragma unroll
                for (int j = 0; j < 4; ++j) {
                    int n = col0 + wc * 64 + j * 16 + (lane & 15);
                    #pragma unroll
                    for (int r = 0; r < 4; ++r)
                        pCb[(size_t)(m0r + r) * 1024 + n] = f2bf(acc[i][j][r]);
                }
            }
        }
    } else if (s < M_WRw) {
        int s2 = s - M_WRr;
        dev_cvtT(W_r, 512, 268, 268, WRWT, 512, 0, s2 % 9, s2 / 9, threadIdx.x, sh);
    } else if (s < M_WOU) {
        int s3 = s - M_WRw;
        dev_cvtT(W_w, 512, 780, 780, WRWT + (size_t)268 * 512, 512, 0,
                 s3 % 25, s3 / 25, threadIdx.x, sh);
    } else if (s < M_ZC1) {
        int s4 = s - M_WOU;
        dev_cvtT(W_ou, 512, 512, 512, WCOMB, 1024, 0, s4 & 15, s4 >> 4,
                 threadIdx.x, sh);
    } else {
        // zpart layer 1 (H0 part only)
        int s5 = s - M_ZC1;
        int colb = s5 & 7, up = s5 >> 3;
        int j = colb * 256 + threadIdx.x;
        const int u0 = up * 64;
        const float* W1 = W_lstm + (size_t)1536 * 2048;
        float acc = 0.f;
        #pragma unroll 4
        for (int t = 0; t < 64; ++t)
            acc = fmaf(H0[512 + u0 + t], W1[(size_t)(1024 + u0 + t) * 2048 + j], acc);
        (ws + OFF_ZPART)[((size_t)8 + up) * 2048 + j] = acc;
    }
}

// ===========================================================================
// Dispatch 3 — LSTM layer 1: K=512 (h1 part) + ZX (X part) in epilogue
// ===========================================================================
__global__ __launch_bounds__(256) void gemm_lstm(
    const unsigned short* __restrict__ A, int lda,
    const unsigned short* __restrict__ Wt, int ldw,
    const float* __restrict__ zpart, const float* __restrict__ b_lstm,
    const float* __restrict__ c0, const unsigned short* __restrict__ ZXP,
    unsigned short* __restrict__ hout)
{
    GEMM_SHARED
    const int row0 = blockIdx.x * 64;
    const int col0 = blockIdx.y * 128;
    GEMM_REGS
    GEMM_MAINLOOP(512)
    LSTM_EPILOGUE(1, 1, hout, 1024, ZXP)
}

// ===========================================================================
// Dispatch 4 — k_hk: heads GEMM + yh GEMM + fused two-stage kmat.
// kmat2: stage1 k = tanh(HCAT @ WK_i + bk) (K=512) -> bf16 into As K-tiles
// (same XOR-swizzle layout as gload16 staging); stage2 kmat = k @ M0B (K=128).
// KMAT layout: [i][2048][256].
// ===========================================================================
__global__ __launch_bounds__(256) void k_hk(
    const unsigned short* __restrict__ HCAT,
    const unsigned short* __restrict__ WRWT,
    const unsigned short* __restrict__ WCOMB,
    const unsigned short* __restrict__ M0B,
    const float* __restrict__ biash,
    float* __restrict__ heads, float* __restrict__ yh,
    float* __restrict__ kmat)
{
    GEMM_SHARED
    const int s = blockIdx.x;
    if (s < H_KM) {
        // ---- heads / yh GEMMs (unchanged R11 paths) ----
        const unsigned short* A = HCAT;  const int lda = 1024;
        const unsigned short* Wt;
        int ldw, row0, col0;
        if (s < H_YH) {
            Wt = WRWT; ldw = 512;
            row0 = (s & 31) * 64; col0 = (s >> 5) * 128;
        } else {
            int p = s - H_YH;
            Wt = WCOMB; ldw = 1024;
            row0 = (p & 31) * 64; col0 = (p >> 5) * 128;
        }
        GEMM_REGS
        GEMM_MAINLOOP(512)
        if (s < H_YH) {
            #pragma unroll
            for (int i = 0; i < 2; ++i) {
                int m0r = row0 + wr * 32 + i * 16 + (lane >> 4) * 4;
                #pragma unroll
                for (int j = 0; j < 4; ++j) {
                    int n = col0 + wc * 64 + j * 16 + (lane & 15);
                    if (n >= 1048) continue;
                    float bv = biash[n];
                    #pragma unroll
                    for (int r = 0; r < 4; ++r)
                        heads[(size_t)(m0r + r) * 1048 + n] = acc[i][j][r] + bv;
                }
            }
        } else {
            #pragma unroll
            for (int i = 0; i < 2; ++i) {
                int m0r = row0 + wr * 32 + i * 16 + (lane >> 4) * 4;
                #pragma unroll
                for (int j = 0; j < 4; ++j) {
                    int n = col0 + wc * 64 + j * 16 + (lane & 15);
                    #pragma unroll
                    for (int r = 0; r < 4; ++r)
                        yh[(size_t)(m0r + r) * 512 + n] = acc[i][j][r];
                }
            }
        }
    } else {
        // ---- kmat2 ----
        int p = s - H_KM;                  // 0..255
        const int ih = p >> 6;             // head 0..3
        const int bt = (p >> 1) & 31;      // b-tile 0..31
        const int nt = p & 1;              // n-tile 0..1
        const int cb = (ih < 2) ? ih * 134 : 268 + (ih - 2) * 390;
        const unsigned short* A  = HCAT;          const int lda = 1024;
        const unsigned short* Wt = WRWT + (size_t)cb * 512;  const int ldw = 512;
        const int row0 = bt * 64;
        const int col0 = 0;
        GEMM_REGS
        GEMM_MAINLOOP(512)                 // stage 1: k-pre = HCAT @ WK_i

        // stage-1 epilogue: P = tanh(acc + bias) -> bf16 into As K-tiles,
        // swizzled so GEMM_FRAGS reads them as A-operand (K=128, 2 tiles).
        #pragma unroll
        for (int i = 0; i < 2; ++i) {
            int rloc = wr * 32 + i * 16 + (lane >> 4) * 4;
            #pragma unroll
            for (int j = 0; j < 4; ++j) {
                int kloc = wc * 64 + j * 16 + (lane & 15);
                float bk = biash[cb + kloc];
                int buf = kloc >> 6;
                int lg = (kloc >> 3) & 7, off = kloc & 7;
                #pragma unroll
                for (int r = 0; r < 4; ++r) {
                    int row = rloc + r;
                    As[buf][row * 64 + (((lg ^ (row & 7)) << 3) | off)] =
                        f2bf(tanhf(acc[i][j][r] + bk));
                }
            }
        }
        // stage 2: re-zero acc, stage M0B K-halves into Ws
        #pragma unroll
        for (int i = 0; i < 2; ++i)
            #pragma unroll
            for (int j = 0; j < 4; ++j) acc[i][j] = (f32x4){0.f, 0.f, 0.f, 0.f};
        const int nb0 = nt * 128;
        #pragma unroll
        for (int kt = 0; kt < 2; ++kt)
            #pragma unroll
            for (int q = 0; q < 4; ++q)
                gload16(M0B + (size_t)(nb0 + q * 32 + (tid >> 3)) * 128 + kt * 64 + ke,
                        &Ws[kt][q * 2048 + tid * 8]);
        __syncthreads();                   // drains vm + lgkm, barrier
        GEMM_FRAGS_AND_MFMA(As[0], Ws[0]);
        GEMM_FRAGS_AND_MFMA(As[1], Ws[1]);
        // epilogue: kmat[(ih*2048 + b)*256 + n]
        #pragma unroll
        for (int i = 0; i < 2; ++i) {
            int rloc = wr * 32 + i * 16 + (lane >> 4) * 4;
            #pragma unroll
            for (int j = 0; j < 4; ++j) {
                int n = nb0 + wc * 64 + j * 16 + (lane & 15);
                #pragma unroll
                for (int r = 0; r < 4; ++r)
                    kmat[((size_t)ih * 2048 + row0 + rloc + r) * 256 + n] =
                        acc[i][j][r];
            }
        }
    }
}

// ===========================================================================
// Dispatch 5 — addressing (4 heads, shuffle reductions); kmat layout [i][b]
// ===========================================================================
__global__ __launch_bounds__(256) void k_addr(
    const float* __restrict__ heads, const float* __restrict__ kmat,
    const float* __restrict__ mnorm, const float* __restrict__ aprev,
    float* __restrict__ at, unsigned short* __restrict__ hcat,
    float* __restrict__ era, float* __restrict__ addv)
{
    __shared__ float red4[4];
    __shared__ float wgs[256];
    __shared__ float sc[6];
    const int b = blockIdx.x, i = blockIdx.y, tid = threadIdx.x;
    const int cb = (i < 2) ? i * 134 : 268 + (i - 2) * 390;
    const float* hd = heads + (size_t)b * 1048 + cb;
    float kv = (tid < 128) ? tanhf(hd[tid]) : 0.f;
    float kn = sqrtf(blk_sum4(kv * kv, red4));
    if (i >= 2 && tid < 128) {
        era [((size_t)b * 2 + (i - 2)) * 128 + tid] = sigf(hd[134 + tid]);
        addv[((size_t)b * 2 + (i - 2)) * 128 + tid] = tanhf(hd[262 + tid]);
    }
    if (tid == 0) {
        sc[0] = softplusf(hd[128]);
        sc[1] = sigf(hd[129]);
        float v0 = hd[130], v1 = hd[131], v2 = hd[132];
        float mx = fmaxf(v0, fmaxf(v1, v2));
        float e0 = expf(v0 - mx), e1 = expf(v1 - mx), e2 = expf(v2 - mx);
        float ssum = e0 + e1 + e2;
        sc[2] = e0 / ssum; sc[3] = e1 / ssum; sc[4] = e2 / ssum;
        sc[5] = softplusf(hd[133]);
    }
    __syncthreads();
    const float beta = sc[0], g = sc[1], s0 = sc[2], s1 = sc[3], s2 = sc[4],
                gamma = sc[5];
    float inner = kmat[((size_t)i * 2048 + b) * 256 + tid];
    float K = inner / (kn * mnorm[tid] + 1e-8f);
    float x = beta * K;
    float mx = blk_max4(x, red4);
    float e = expf(x - mx);
    float se = blk_sum4(e, red4);
    float wc = e / se;
    float wg = g * wc + (1.f - g) * aprev[i * 256 + tid];
    wgs[tid] = wg;
    __syncthreads();
    float wconv = s0 * wg + s1 * wgs[(tid + 255) & 255] + s2 * wgs[(tid + 1) & 255];
    float wsh = powf(wconv, gamma);
    float ssum = blk_sum4(wsh, red4);
    float w = wsh / ssum;
    if (i < 2) hcat[(size_t)b * 1024 + 512 + i * 256 + tid] = f2bf(w);
    else       at[((size_t)(i - 2) * Bn + b) * 256 + tid] = w;
}

// ===========================================================================
// Dispatch 6 — k_tail: out GEMM (K=512 A-part + yh base + clip) + memt.
// ===========================================================================
__global__ __launch_bounds__(256) void k_tail(
    const unsigned short* __restrict__ HCAT,
    const unsigned short* __restrict__ WCOMB,
    const float* __restrict__ yh, const float* __restrict__ b_ou,
    const float* __restrict__ m0, const float* __restrict__ at,
    const float* __restrict__ era, const float* __restrict__ addv,
    float* __restrict__ out)
{
    GEMM_SHARED
    const int s = blockIdx.x;
    if (s < T_MEM) {
        // ---- out GEMM: y = clip(yh + A-cols @ WCOMB[k 512:] + b_ou) ----
        const unsigned short* A  = HCAT + 512;        const int lda = 1024;
        const unsigned short* Wt = WCOMB + 512;       const int ldw = 1024;
        const int row0 = (s & 31) * 64;
        const int col0 = (s >> 5) * 128;
        GEMM_REGS
        GEMM_MAINLOOP(512)
        #pragma unroll
        for (int i = 0; i < 2; ++i) {
            int m0r = row0 + wr * 32 + i * 16 + (lane >> 4) * 4;
            #pragma unroll
            for (int j = 0; j < 4; ++j) {
                int n = col0 + wc * 64 + j * 16 + (lane & 15);
                if (n >= 512) continue;
                float bv = b_ou[n];
                #pragma unroll
                for (int r = 0; r < 4; ++r) {
                    float v = acc[i][j][r] + bv + yh[(size_t)(m0r + r) * 512 + n];
                    out[(size_t)(m0r + r) * 512 + n] = fminf(fmaxf(v, -20.f), 20.f);
                }
            }
        }
    } else {
        // ---- memt: 8 batch rows per block, m0 reused 8x, NT stores ----
        const int tid = threadIdx.x;
        const int b0 = (s - T_MEM) * 8;
        float (*at_s)[8][256] = (float(*)[8][256])(&As[0][0]);     // 16 KB
        float (*er_s)[8][128] = (float(*)[8][128])(&Ws[0][0]);     // 8 KB
        float (*ad_s)[8][128] = (float(*)[8][128])(&Ws[0][4096]);  // 8 KB
        for (int t = tid; t < 1024; t += 256) {
            int i = t >> 9, rem = t & 511;
            int bb = rem >> 6, n4 = rem & 63;
            ((float4*)&at_s[i][bb][0])[n4] =
                ((const float4*)(at + ((size_t)i * Bn + b0 + bb) * 256))[n4];
        }
        for (int t = tid; t < 512; t += 256) {
            int i = t >> 8, rem = t & 255;
            int bb = rem >> 5, m4 = rem & 31;
            ((float4*)&er_s[i][bb][0])[m4] =
                ((const float4*)(era + ((size_t)(b0 + bb) * 2 + i) * 128))[m4];
            ((float4*)&ad_s[i][bb][0])[m4] =
                ((const float4*)(addv + ((size_t)(b0 + bb) * 2 + i) * 128))[m4];
        }
        __syncthreads();
        const float4* m0v = (const float4*)m0;
        float4* outv = (float4*)(out + (size_t)Bn * Un);
        for (int pos = tid; pos < 8192; pos += 256) {
            int mq = pos & 31, n = pos >> 5;
            float4 t0 = m0v[pos];
            #pragma unroll
            for (int bb = 0; bb < 8; ++bb) {
                float w0 = at_s[0][bb][n], w1 = at_s[1][bb][n];
                float4 e0 = *(const float4*)&er_s[0][bb][mq * 4];
                float4 a0 = *(const float4*)&ad_s[0][bb][mq * 4];
                float4 e1 = *(const float4*)&er_s[1][bb][mq * 4];
                float4 a1 = *(const float4*)&ad_s[1][bb][mq * 4];
                float4 t = t0;
#define UPD(c) { t.c = t.c * (1.f - w0 * e0.c) + w0 * a0.c; \
                 t.c = t.c * (1.f - w1 * e1.c) + w1 * a1.c; }
                UPD(x) UPD(y) UPD(z) UPD(w)
#undef UPD
                __builtin_nontemporal_store(*(f32x4*)&t,
                    (f32x4*)&outv[(size_t)(b0 + bb) * 8192 + pos]);
            }
        }
    }
}

extern "C" void kernel_launch(void* const* d_in, const int* in_sizes, int n_in,
                              void* d_out, int out_size, void* d_ws, size_t ws_size,
                              hipStream_t stream)
{
    const float* X      = (const float*)d_in[0];
    const float* m0     = (const float*)d_in[1];
    const float* H0     = (const float*)d_in[2];
    const float* C0     = (const float*)d_in[3];
    const float* R0     = (const float*)d_in[4];
    const float* A0     = (const float*)d_in[5];
    const float* W_prep = (const float*)d_in[6];
    const float* b_prep = (const float*)d_in[7];
    const float* W_lstm = (const float*)d_in[8];
    const float* b_lstm = (const float*)d_in[9];
    const float* W_r    = (const float*)d_in[10];
    const float* b_r    = (const float*)d_in[11];
    const float* W_w    = (const float*)d_in[12];
    const float* b_w    = (const float*)d_in[13];
    const float* W_ou   = (const float*)d_in[14];
    const float* b_ou   = (const float*)d_in[15];
    float* ws  = (float*)d_ws;
    float* out = (float*)d_out;

    unsigned short* XHB   = (unsigned short*)(ws + OFF_XHB);
    unsigned short* HCAT  = (unsigned short*)(ws + OFF_HCAT);
    unsigned short* W1T   = (unsigned short*)(ws + OFF_W1T);
    unsigned short* WRWT  = (unsigned short*)(ws + OFF_WRWT);
    unsigned short* WCOMB = (unsigned short*)(ws + OFF_WCOMB);
    unsigned short* M0B   = (unsigned short*)(ws + OFF_M0B);
    unsigned short* ZX    = (unsigned short*)(ws + OFF_KMAT);

    // 1. critical prep
    k_prep<<<P_END, 256, 0, stream>>>(
        X, m0, H0, R0, A0, W_prep, b_prep, W_lstm, b_r, b_w, W_ou, ws);

    // 2. LSTM0 + ZX (L1 X-part) + pfold + late prep (concurrent)
    k_mid<<<M_END, 256, 0, stream>>>(
        W_lstm, W_r, W_w, W_ou, H0, b_lstm, C0, ws);

    // 3. LSTM layer 1 (K=512 h1-part; ZX added in epilogue)
    gemm_lstm<<<dim3(32, 16), 256, 0, stream>>>(
        XHB + 512, 1024, W1T + 512, 1024, ws + OFF_ZPART, b_lstm, C0, ZX, HCAT);

    // 4. heads + yh + fused kmat (one dispatch; kmat no longer serialized)
    k_hk<<<H_END, 256, 0, stream>>>(
        HCAT, WRWT, WCOMB, M0B, ws + OFF_BIASH, ws + OFF_HEADS, ws + OFF_YH,
        ws + OFF_KMAT);

    // 5. addressing
    k_addr<<<dim3(Bn, 4), 256, 0, stream>>>(
        ws + OFF_HEADS, ws + OFF_KMAT, ws + OFF_MNORM, ws + OFF_APREV,
        ws + OFF_AT, HCAT, ws + OFF_ERA, ws + OFF_ADD);

    // 6. out GEMM (K=512 + yh) + memt (overlapped)
    k_tail<<<T_END, 256, 0, stream>>>(
        HCAT, WCOMB, ws + OFF_YH, b_ou, m0, ws + OFF_AT, ws + OFF_ERA,
        ws + OFF_ADD, out);
}